// Round 1
// baseline (10915.961 us; speedup 1.0000x reference)
//
#include <hip/hip_runtime.h>
#include <math.h>

#define HB 8
#define TT 1024
#define EE 128
#define DD 512
#define DDI 1024
#define NSTATE 16
#define DCC 4
#define RRANK 32
#define NTT 6
#define NMM 8
#define FFF 2048
#define MM (HB*TT)   /* 8192 rows */
#define EPSV 1e-5f

// ---------------------------------------------------------------------------
// Generic fp32 GEMM: C(M,N) = act( A(M,K; lda) @ W(N,K)^T + bias )
// act: 0 none, 1 relu, 2 softplus
// Tiles 64x64, 256 threads, 4x4 per thread, K-step 16.
// ---------------------------------------------------------------------------
__global__ __launch_bounds__(256) void gemm_k(
    const float* __restrict__ A, int lda,
    const float* __restrict__ W,
    const float* __restrict__ bias,
    float* __restrict__ C,
    int N, int K, int act)
{
  __shared__ __align__(16) float As[16][64];
  __shared__ __align__(16) float Bs[16][64];
  const int tid = threadIdx.x;
  const int m0 = blockIdx.y * 64;
  const int n0 = blockIdx.x * 64;
  const int tr = tid >> 4;        // 0..15
  const int tc = tid & 15;        // 0..15
  const int lr = tid >> 2;        // 0..63 (tile row to load)
  const int lk = (tid & 3) << 2;  // 0,4,8,12 (k offset)

  float acc[4][4];
#pragma unroll
  for (int i = 0; i < 4; i++)
#pragma unroll
    for (int j = 0; j < 4; j++) acc[i][j] = 0.f;

  for (int k0 = 0; k0 < K; k0 += 16) {
    float4 av = *(const float4*)&A[(size_t)(m0 + lr) * lda + k0 + lk];
    float4 wv = *(const float4*)&W[(size_t)(n0 + lr) * K + k0 + lk];
    __syncthreads();
    As[lk + 0][lr] = av.x; As[lk + 1][lr] = av.y;
    As[lk + 2][lr] = av.z; As[lk + 3][lr] = av.w;
    Bs[lk + 0][lr] = wv.x; Bs[lk + 1][lr] = wv.y;
    Bs[lk + 2][lr] = wv.z; Bs[lk + 3][lr] = wv.w;
    __syncthreads();
#pragma unroll
    for (int kk = 0; kk < 16; ++kk) {
      float4 a = *(const float4*)&As[kk][tr * 4];
      float4 b = *(const float4*)&Bs[kk][tc * 4];
      float av4[4] = {a.x, a.y, a.z, a.w};
      float bv4[4] = {b.x, b.y, b.z, b.w};
#pragma unroll
      for (int i = 0; i < 4; i++)
#pragma unroll
        for (int j = 0; j < 4; j++) acc[i][j] += av4[i] * bv4[j];
    }
  }

#pragma unroll
  for (int i = 0; i < 4; i++) {
    const int m = m0 + tr * 4 + i;
    float4 o;
    float* po = (float*)&o;
#pragma unroll
    for (int j = 0; j < 4; j++) {
      float v = acc[i][j];
      const int n = n0 + tc * 4 + j;
      if (bias) v += bias[n];
      if (act == 1) v = fmaxf(v, 0.f);
      else if (act == 2) v = fmaxf(v, 0.f) + log1pf(__expf(-fabsf(v)));
      po[j] = v;
    }
    *(float4*)&C[(size_t)m * N + n0 + tc * 4] = o;
  }
}

// ---------------------------------------------------------------------------
// Attention: qkv (M,384) rows [q|k|v], head dim 16, scale 0.25.
// One thread per query row per (b,h). Two passes (max, then exp/acc).
// grid = (T/256, B*H), block 256.
// ---------------------------------------------------------------------------
__global__ __launch_bounds__(256) void attn_k(const float* __restrict__ qkv,
                                              float* __restrict__ o)
{
  __shared__ __align__(16) float Ks[128 * 16];
  __shared__ __align__(16) float Vs[128 * 16];
  const int tid = threadIdx.x;
  const int bh = blockIdx.y;
  const int b = bh >> 3;
  const int h = bh & 7;
  const int t = blockIdx.x * 256 + tid;

  const float* qp = qkv + ((size_t)(b * TT + t)) * 384 + h * 16;
  float q[16];
#pragma unroll
  for (int p = 0; p < 4; p++) {
    float4 qv = *(const float4*)&qp[p * 4];
    q[p * 4 + 0] = qv.x; q[p * 4 + 1] = qv.y; q[p * 4 + 2] = qv.z; q[p * 4 + 3] = qv.w;
  }

  const size_t baseK = ((size_t)b * TT) * 384 + 128 + h * 16;

  // pass 1: row max
  float mx = -1e30f;
  for (int kt = 0; kt < TT; kt += 128) {
    __syncthreads();
    for (int idx = tid; idx < 512; idx += 256) {
      int row = idx >> 2, part = idx & 3;
      *(float4*)&Ks[row * 16 + part * 4] =
          *(const float4*)&qkv[baseK + (size_t)(kt + row) * 384 + part * 4];
    }
    __syncthreads();
    for (int j = 0; j < 128; j++) {
      float4 k0 = *(const float4*)&Ks[j * 16 + 0];
      float4 k1 = *(const float4*)&Ks[j * 16 + 4];
      float4 k2 = *(const float4*)&Ks[j * 16 + 8];
      float4 k3 = *(const float4*)&Ks[j * 16 + 12];
      float s = q[0]*k0.x + q[1]*k0.y + q[2]*k0.z + q[3]*k0.w
              + q[4]*k1.x + q[5]*k1.y + q[6]*k1.z + q[7]*k1.w
              + q[8]*k2.x + q[9]*k2.y + q[10]*k2.z + q[11]*k2.w
              + q[12]*k3.x + q[13]*k3.y + q[14]*k3.z + q[15]*k3.w;
      mx = fmaxf(mx, s * 0.25f);
    }
  }

  // pass 2: exp / accumulate
  float l = 0.f;
  float acc[16];
#pragma unroll
  for (int d = 0; d < 16; d++) acc[d] = 0.f;
  for (int kt = 0; kt < TT; kt += 128) {
    __syncthreads();
    for (int idx = tid; idx < 512; idx += 256) {
      int row = idx >> 2, part = idx & 3;
      *(float4*)&Ks[row * 16 + part * 4] =
          *(const float4*)&qkv[baseK + (size_t)(kt + row) * 384 + part * 4];
      *(float4*)&Vs[row * 16 + part * 4] =
          *(const float4*)&qkv[baseK + 128 + (size_t)(kt + row) * 384 + part * 4];
    }
    __syncthreads();
    for (int j = 0; j < 128; j++) {
      float4 k0 = *(const float4*)&Ks[j * 16 + 0];
      float4 k1 = *(const float4*)&Ks[j * 16 + 4];
      float4 k2 = *(const float4*)&Ks[j * 16 + 8];
      float4 k3 = *(const float4*)&Ks[j * 16 + 12];
      float s = q[0]*k0.x + q[1]*k0.y + q[2]*k0.z + q[3]*k0.w
              + q[4]*k1.x + q[5]*k1.y + q[6]*k1.z + q[7]*k1.w
              + q[8]*k2.x + q[9]*k2.y + q[10]*k2.z + q[11]*k2.w
              + q[12]*k3.x + q[13]*k3.y + q[14]*k3.z + q[15]*k3.w;
      float p = __expf(s * 0.25f - mx);
      l += p;
      float4 v0 = *(const float4*)&Vs[j * 16 + 0];
      float4 v1 = *(const float4*)&Vs[j * 16 + 4];
      float4 v2 = *(const float4*)&Vs[j * 16 + 8];
      float4 v3 = *(const float4*)&Vs[j * 16 + 12];
      acc[0] += p*v0.x; acc[1] += p*v0.y; acc[2] += p*v0.z; acc[3] += p*v0.w;
      acc[4] += p*v1.x; acc[5] += p*v1.y; acc[6] += p*v1.z; acc[7] += p*v1.w;
      acc[8] += p*v2.x; acc[9] += p*v2.y; acc[10]+= p*v2.z; acc[11]+= p*v2.w;
      acc[12]+= p*v3.x; acc[13]+= p*v3.y; acc[14]+= p*v3.z; acc[15]+= p*v3.w;
    }
  }
  const float inv = 1.f / l;
  float* op = o + ((size_t)(b * TT + t)) * 128 + h * 16;
#pragma unroll
  for (int p = 0; p < 4; p++) {
    float4 ov;
    ov.x = acc[p*4+0]*inv; ov.y = acc[p*4+1]*inv;
    ov.z = acc[p*4+2]*inv; ov.w = acc[p*4+3]*inv;
    *(float4*)&op[p * 4] = ov;
  }
}

// ---------------------------------------------------------------------------
// out = LN(a + bvec) * w + bb   (rows of 128; wave per row; 4 rows/block)
// ---------------------------------------------------------------------------
__global__ __launch_bounds__(256) void add_ln_k(
    const float* __restrict__ a, const float* __restrict__ bvec,
    const float* __restrict__ w, const float* __restrict__ bb,
    float* __restrict__ out)
{
  const int tid = threadIdx.x;
  const int wave = tid >> 6, lane = tid & 63;
  const size_t row = (size_t)blockIdx.x * 4 + wave;
  const float* pa = a + row * 128;
  const float* pb = bvec + row * 128;
  float v0 = pa[lane] + pb[lane];
  float v1 = pa[lane + 64] + pb[lane + 64];
  float s1 = v0 + v1, s2 = v0 * v0 + v1 * v1;
#pragma unroll
  for (int off = 32; off; off >>= 1) {
    s1 += __shfl_down(s1, off);
    s2 += __shfl_down(s2, off);
  }
  s1 = __shfl(s1, 0); s2 = __shfl(s2, 0);
  const float mean = s1 * (1.f / 128.f);
  const float var = s2 * (1.f / 128.f) - mean * mean;
  const float rs = rsqrtf(var + EPSV);
  out[row * 128 + lane]      = (v0 - mean) * rs * w[lane] + bb[lane];
  out[row * 128 + lane + 64] = (v1 - mean) * rs * w[lane + 64] + bb[lane + 64];
}

// ---------------------------------------------------------------------------
// Depthwise causal conv (DC=4) over xi = xz[:, :1024] (row stride 2048) + SiLU
// thread per (m, di)
// ---------------------------------------------------------------------------
__global__ __launch_bounds__(256) void conv_silu_k(
    const float* __restrict__ xz, const float* __restrict__ cw,
    const float* __restrict__ cb, float* __restrict__ out)
{
  const int idx = blockIdx.x * 256 + threadIdx.x;   // 0 .. M*1024-1
  const int di = idx & 1023;
  const int m = idx >> 10;
  const int t = m & (TT - 1);
  float acc = cb[di];
#pragma unroll
  for (int k = 0; k < 4; k++) {
    int tt = t + k - 3;
    if (tt >= 0) acc += xz[(size_t)(m + k - 3) * 2048 + di] * cw[di * 4 + k];
  }
  out[(size_t)m * 1024 + di] = acc / (1.f + __expf(-acc));
}

// ---------------------------------------------------------------------------
// Selective scan. thread per (b, di); 16 states in registers; sequential T.
// Fuses  y = scan_y + D*x ;  y *= silu(z)  (z = xz[:,1024+di]).
// grid (DI/64, B), block 64.
// ---------------------------------------------------------------------------
__global__ __launch_bounds__(64) void scan_k(
    const float* __restrict__ dt,    // (M,1024)
    const float* __restrict__ dbc,   // (M,64)  [dt_r | B | C]
    const float* __restrict__ xi,    // (M,1024)
    const float* __restrict__ xz,    // (M,2048)
    const float* __restrict__ Alog,  // (1024,16)
    const float* __restrict__ Dp,    // (1024)
    float* __restrict__ Y)           // (M,1024)
{
  const int di = blockIdx.x * 64 + threadIdx.x;
  const int b = blockIdx.y;
  float A[16];
#pragma unroll
  for (int n = 0; n < 16; n++) A[n] = -__expf(Alog[di * 16 + n]);
  const float Dv = Dp[di];
  float h[16];
#pragma unroll
  for (int n = 0; n < 16; n++) h[n] = 0.f;
  const size_t rbase = (size_t)b * TT;
  for (int t = 0; t < TT; t++) {
    const size_t m = rbase + t;
    const float dtv = dt[m * 1024 + di];
    const float xv = xi[m * 1024 + di];
    const float zv = xz[m * 2048 + 1024 + di];
    float Bv[16], Cv[16];
#pragma unroll
    for (int n = 0; n < 16; n++) {
      Bv[n] = dbc[m * 64 + 32 + n];
      Cv[n] = dbc[m * 64 + 48 + n];
    }
    const float dtx = dtv * xv;
    float y = 0.f;
#pragma unroll
    for (int n = 0; n < 16; n++) {
      const float dA = __expf(dtv * A[n]);
      h[n] = h[n] * dA + dtx * Bv[n];
      y += h[n] * Cv[n];
    }
    y += Dv * xv;
    y *= zv / (1.f + __expf(-zv));
    Y[m * 1024 + di] = y;
  }
}

// ---------------------------------------------------------------------------
extern "C" void kernel_launch(void* const* d_in, const int* in_sizes, int n_in,
                              void* d_out, int out_size, void* d_ws, size_t ws_size,
                              hipStream_t stream)
{
  const float* emb      = (const float*)d_in[0];
  const float* t_wqkv   = (const float*)d_in[1];
  const float* t_bqkv   = (const float*)d_in[2];
  const float* t_wo     = (const float*)d_in[3];
  const float* t_bo     = (const float*)d_in[4];
  const float* t_ln1w   = (const float*)d_in[5];
  const float* t_ln1b   = (const float*)d_in[6];
  const float* t_w1     = (const float*)d_in[7];
  const float* t_b1     = (const float*)d_in[8];
  const float* t_w2     = (const float*)d_in[9];
  const float* t_b2     = (const float*)d_in[10];
  const float* t_ln2w   = (const float*)d_in[11];
  const float* t_ln2b   = (const float*)d_in[12];
  const float* w_in     = (const float*)d_in[13];
  const float* b_in     = (const float*)d_in[14];
  const float* m_inproj = (const float*)d_in[15];
  const float* m_convw  = (const float*)d_in[16];
  const float* m_convb  = (const float*)d_in[17];
  const float* m_xproj  = (const float*)d_in[18];
  const float* m_dtw    = (const float*)d_in[19];
  const float* m_dtb    = (const float*)d_in[20];
  const float* m_Alog   = (const float*)d_in[21];
  const float* m_D      = (const float*)d_in[22];
  const float* m_outproj= (const float*)d_in[23];
  const float* w_out    = (const float*)d_in[24];
  const float* b_out    = (const float*)d_in[25];

  float* ws = (float*)d_ws;
  float* X0   = ws;                               // M*512
  float* X1   = X0 + (size_t)MM * 512;            // M*512
  float* Abuf = X1 + (size_t)MM * 512;            // M*2048 (qkv | ff1 | xz)
  float* Bf   = Abuf + (size_t)MM * 2048;         // M*1024 (xi_act)
  float* Cf   = Bf + (size_t)MM * 1024;           // M*1024 (wo-out | ff2 | dt)
  float* Yb   = Cf + (size_t)MM * 1024;           // M*1024 (attn o | scan y)
  float* Db   = Yb + (size_t)MM * 1024;           // M*64   (dbc)

  dim3 blk(256);
  auto gemm = [&](const float* A, int lda, const float* W, const float* bias,
                  float* C, int N, int K, int act) {
    dim3 g(N / 64, MM / 64);
    hipLaunchKernelGGL(gemm_k, g, blk, 0, stream, A, lda, W, bias, C, N, K, act);
  };

  const float* x = emb;
  for (int l = 0; l < NTT; l++) {
    gemm(x, 128, t_wqkv + (size_t)l * 384 * 128, t_bqkv + l * 384, Abuf, 384, 128, 0);
    hipLaunchKernelGGL(attn_k, dim3(TT / 256, HB * 8), blk, 0, stream, Abuf, Yb);
    gemm(Yb, 128, t_wo + (size_t)l * 128 * 128, t_bo + l * 128, Cf, 128, 128, 0);
    hipLaunchKernelGGL(add_ln_k, dim3(MM / 4), blk, 0, stream,
                       x, Cf, t_ln1w + l * 128, t_ln1b + l * 128, X0);
    gemm(X0, 128, t_w1 + (size_t)l * 2048 * 128, t_b1 + l * 2048, Abuf, 2048, 128, 1);
    gemm(Abuf, 2048, t_w2 + (size_t)l * 128 * 2048, t_b2 + l * 128, Cf, 128, 2048, 0);
    hipLaunchKernelGGL(add_ln_k, dim3(MM / 4), blk, 0, stream,
                       X0, Cf, t_ln2w + l * 128, t_ln2b + l * 128, X0);
    x = X0;
  }

  gemm(X0, 128, w_in, b_in, X1, 512, 128, 0);

  float* xc = X1;
  float* xo = X0;
  for (int l = 0; l < NMM; l++) {
    gemm(xc, 512, m_inproj + (size_t)l * 2048 * 512, nullptr, Abuf, 2048, 512, 0);
    hipLaunchKernelGGL(conv_silu_k, dim3(MM * 1024 / 256), blk, 0, stream,
                       Abuf, m_convw + (size_t)l * 1024 * 4, m_convb + l * 1024, Bf);
    gemm(Bf, 1024, m_xproj + (size_t)l * 64 * 1024, nullptr, Db, 64, 1024, 0);
    gemm(Db, 64, m_dtw + (size_t)l * 1024 * 32, m_dtb + l * 1024, Cf, 1024, 32, 2);
    hipLaunchKernelGGL(scan_k, dim3(DDI / 64, HB), dim3(64), 0, stream,
                       Cf, Db, Bf, Abuf,
                       m_Alog + (size_t)l * 1024 * 16, m_D + l * 1024, Yb);
    gemm(Yb, 1024, m_outproj + (size_t)l * 512 * 1024, nullptr, xo, 512, 1024, 0);
    float* tmp = xc; xc = xo; xo = tmp;
  }

  gemm(xc, 512, w_out, b_out, (float*)d_out, 128, 512, 0);
}

// Round 2
// 7267.825 us; speedup vs baseline: 1.5020x; 1.5020x over previous
//
#include <hip/hip_runtime.h>
#include <math.h>

#define HB 8
#define TT 1024
#define EE 128
#define DD 512
#define DDI 1024
#define NSTATE 16
#define NTT 6
#define NMM 8
#define FFF 2048
#define MM (HB*TT)   /* 8192 rows */
#define EPSV 1e-5f
#define CHUNK 64
#define NCH (TT/CHUNK)   /* 16 */

// ---------------------------------------------------------------------------
// Generic fp32 GEMM: C(M,N) = act( A(M,K; lda) @ W(N,K)^T + bias )
// act: 0 none, 1 relu, 2 softplus.  Tiles 64x64, 256 thr, 4x4/thr, K-step 16.
// ---------------------------------------------------------------------------
__global__ __launch_bounds__(256) void gemm_k(
    const float* __restrict__ A, int lda,
    const float* __restrict__ W,
    const float* __restrict__ bias,
    float* __restrict__ C,
    int N, int K, int act)
{
  __shared__ __align__(16) float As[16][64];
  __shared__ __align__(16) float Bs[16][64];
  const int tid = threadIdx.x;
  const int m0 = blockIdx.y * 64;
  const int n0 = blockIdx.x * 64;
  const int tr = tid >> 4;
  const int tc = tid & 15;
  const int lr = tid >> 2;
  const int lk = (tid & 3) << 2;

  float acc[4][4];
#pragma unroll
  for (int i = 0; i < 4; i++)
#pragma unroll
    for (int j = 0; j < 4; j++) acc[i][j] = 0.f;

  for (int k0 = 0; k0 < K; k0 += 16) {
    float4 av = *(const float4*)&A[(size_t)(m0 + lr) * lda + k0 + lk];
    float4 wv = *(const float4*)&W[(size_t)(n0 + lr) * K + k0 + lk];
    __syncthreads();
    As[lk + 0][lr] = av.x; As[lk + 1][lr] = av.y;
    As[lk + 2][lr] = av.z; As[lk + 3][lr] = av.w;
    Bs[lk + 0][lr] = wv.x; Bs[lk + 1][lr] = wv.y;
    Bs[lk + 2][lr] = wv.z; Bs[lk + 3][lr] = wv.w;
    __syncthreads();
#pragma unroll
    for (int kk = 0; kk < 16; ++kk) {
      float4 a = *(const float4*)&As[kk][tr * 4];
      float4 b = *(const float4*)&Bs[kk][tc * 4];
      float av4[4] = {a.x, a.y, a.z, a.w};
      float bv4[4] = {b.x, b.y, b.z, b.w};
#pragma unroll
      for (int i = 0; i < 4; i++)
#pragma unroll
        for (int j = 0; j < 4; j++) acc[i][j] += av4[i] * bv4[j];
    }
  }

#pragma unroll
  for (int i = 0; i < 4; i++) {
    const int m = m0 + tr * 4 + i;
    float4 o;
    float* po = (float*)&o;
#pragma unroll
    for (int j = 0; j < 4; j++) {
      float v = acc[i][j];
      const int n = n0 + tc * 4 + j;
      if (bias) v += bias[n];
      if (act == 1) v = fmaxf(v, 0.f);
      else if (act == 2) v = fmaxf(v, 0.f) + log1pf(__expf(-fabsf(v)));
      po[j] = v;
    }
    *(float4*)&C[(size_t)m * N + n0 + tc * 4] = o;
  }
}

// ---------------------------------------------------------------------------
// Big-tile fp32 GEMM: 128x128 tile, 256 thr, 8x8/thr (split 4+4), K-step 8.
// ---------------------------------------------------------------------------
__global__ __launch_bounds__(256) void gemm128_k(
    const float* __restrict__ A, int lda,
    const float* __restrict__ W,
    const float* __restrict__ bias,
    float* __restrict__ C,
    int N, int K, int act)
{
  __shared__ __align__(16) float As[8][128];
  __shared__ __align__(16) float Bs[8][128];
  const int tid = threadIdx.x;
  const int m0 = blockIdx.y * 128;
  const int n0 = blockIdx.x * 128;
  const int lr = tid >> 1;            // 0..127
  const int lk = (tid & 1) * 4;       // 0 or 4
  const int tr = tid >> 4;            // 0..15
  const int tc = tid & 15;            // 0..15
  const int r0 = tr * 4;
  const int c0 = tc * 4;

  float acc[8][8];
#pragma unroll
  for (int i = 0; i < 8; i++)
#pragma unroll
    for (int j = 0; j < 8; j++) acc[i][j] = 0.f;

  for (int k0 = 0; k0 < K; k0 += 8) {
    float4 av = *(const float4*)&A[(size_t)(m0 + lr) * lda + k0 + lk];
    float4 wv = *(const float4*)&W[(size_t)(n0 + lr) * K + k0 + lk];
    __syncthreads();
    As[lk + 0][lr] = av.x; As[lk + 1][lr] = av.y;
    As[lk + 2][lr] = av.z; As[lk + 3][lr] = av.w;
    Bs[lk + 0][lr] = wv.x; Bs[lk + 1][lr] = wv.y;
    Bs[lk + 2][lr] = wv.z; Bs[lk + 3][lr] = wv.w;
    __syncthreads();
#pragma unroll
    for (int kk = 0; kk < 8; ++kk) {
      float4 alo = *(const float4*)&As[kk][r0];
      float4 ahi = *(const float4*)&As[kk][64 + r0];
      float4 blo = *(const float4*)&Bs[kk][c0];
      float4 bhi = *(const float4*)&Bs[kk][64 + c0];
      float a8[8] = {alo.x, alo.y, alo.z, alo.w, ahi.x, ahi.y, ahi.z, ahi.w};
      float b8[8] = {blo.x, blo.y, blo.z, blo.w, bhi.x, bhi.y, bhi.z, bhi.w};
#pragma unroll
      for (int i = 0; i < 8; i++)
#pragma unroll
        for (int j = 0; j < 8; j++) acc[i][j] += a8[i] * b8[j];
    }
  }

#pragma unroll
  for (int ih = 0; ih < 2; ih++) {
#pragma unroll
    for (int i = 0; i < 4; i++) {
      const int m = m0 + ih * 64 + r0 + i;
#pragma unroll
      for (int jh = 0; jh < 2; jh++) {
        const int nb = n0 + jh * 64 + c0;
        float4 o;
        float* po = (float*)&o;
#pragma unroll
        for (int j = 0; j < 4; j++) {
          float v = acc[ih * 4 + i][jh * 4 + j];
          if (bias) v += bias[nb + j];
          if (act == 1) v = fmaxf(v, 0.f);
          else if (act == 2) v = fmaxf(v, 0.f) + log1pf(__expf(-fabsf(v)));
          po[j] = v;
        }
        *(float4*)&C[(size_t)m * N + nb] = o;
      }
    }
  }
}

// ---------------------------------------------------------------------------
// Attention: qkv (M,384) rows [q|k|v], head dim 16, scale 0.25.
// ---------------------------------------------------------------------------
__global__ __launch_bounds__(256) void attn_k(const float* __restrict__ qkv,
                                              float* __restrict__ o)
{
  __shared__ __align__(16) float Ks[128 * 16];
  __shared__ __align__(16) float Vs[128 * 16];
  const int tid = threadIdx.x;
  const int bh = blockIdx.y;
  const int b = bh >> 3;
  const int h = bh & 7;
  const int t = blockIdx.x * 256 + tid;

  const float* qp = qkv + ((size_t)(b * TT + t)) * 384 + h * 16;
  float q[16];
#pragma unroll
  for (int p = 0; p < 4; p++) {
    float4 qv = *(const float4*)&qp[p * 4];
    q[p * 4 + 0] = qv.x; q[p * 4 + 1] = qv.y; q[p * 4 + 2] = qv.z; q[p * 4 + 3] = qv.w;
  }

  const size_t baseK = ((size_t)b * TT) * 384 + 128 + h * 16;

  float mx = -1e30f;
  for (int kt = 0; kt < TT; kt += 128) {
    __syncthreads();
    for (int idx = tid; idx < 512; idx += 256) {
      int row = idx >> 2, part = idx & 3;
      *(float4*)&Ks[row * 16 + part * 4] =
          *(const float4*)&qkv[baseK + (size_t)(kt + row) * 384 + part * 4];
    }
    __syncthreads();
    for (int j = 0; j < 128; j++) {
      float4 k0 = *(const float4*)&Ks[j * 16 + 0];
      float4 k1 = *(const float4*)&Ks[j * 16 + 4];
      float4 k2 = *(const float4*)&Ks[j * 16 + 8];
      float4 k3 = *(const float4*)&Ks[j * 16 + 12];
      float s = q[0]*k0.x + q[1]*k0.y + q[2]*k0.z + q[3]*k0.w
              + q[4]*k1.x + q[5]*k1.y + q[6]*k1.z + q[7]*k1.w
              + q[8]*k2.x + q[9]*k2.y + q[10]*k2.z + q[11]*k2.w
              + q[12]*k3.x + q[13]*k3.y + q[14]*k3.z + q[15]*k3.w;
      mx = fmaxf(mx, s * 0.25f);
    }
  }

  float l = 0.f;
  float acc[16];
#pragma unroll
  for (int d = 0; d < 16; d++) acc[d] = 0.f;
  for (int kt = 0; kt < TT; kt += 128) {
    __syncthreads();
    for (int idx = tid; idx < 512; idx += 256) {
      int row = idx >> 2, part = idx & 3;
      *(float4*)&Ks[row * 16 + part * 4] =
          *(const float4*)&qkv[baseK + (size_t)(kt + row) * 384 + part * 4];
      *(float4*)&Vs[row * 16 + part * 4] =
          *(const float4*)&qkv[baseK + 128 + (size_t)(kt + row) * 384 + part * 4];
    }
    __syncthreads();
    for (int j = 0; j < 128; j++) {
      float4 k0 = *(const float4*)&Ks[j * 16 + 0];
      float4 k1 = *(const float4*)&Ks[j * 16 + 4];
      float4 k2 = *(const float4*)&Ks[j * 16 + 8];
      float4 k3 = *(const float4*)&Ks[j * 16 + 12];
      float s = q[0]*k0.x + q[1]*k0.y + q[2]*k0.z + q[3]*k0.w
              + q[4]*k1.x + q[5]*k1.y + q[6]*k1.z + q[7]*k1.w
              + q[8]*k2.x + q[9]*k2.y + q[10]*k2.z + q[11]*k2.w
              + q[12]*k3.x + q[13]*k3.y + q[14]*k3.z + q[15]*k3.w;
      float p = __expf(s * 0.25f - mx);
      l += p;
      float4 v0 = *(const float4*)&Vs[j * 16 + 0];
      float4 v1 = *(const float4*)&Vs[j * 16 + 4];
      float4 v2 = *(const float4*)&Vs[j * 16 + 8];
      float4 v3 = *(const float4*)&Vs[j * 16 + 12];
      acc[0] += p*v0.x; acc[1] += p*v0.y; acc[2] += p*v0.z; acc[3] += p*v0.w;
      acc[4] += p*v1.x; acc[5] += p*v1.y; acc[6] += p*v1.z; acc[7] += p*v1.w;
      acc[8] += p*v2.x; acc[9] += p*v2.y; acc[10]+= p*v2.z; acc[11]+= p*v2.w;
      acc[12]+= p*v3.x; acc[13]+= p*v3.y; acc[14]+= p*v3.z; acc[15]+= p*v3.w;
    }
  }
  const float inv = 1.f / l;
  float* op = o + ((size_t)(b * TT + t)) * 128 + h * 16;
#pragma unroll
  for (int p = 0; p < 4; p++) {
    float4 ov;
    ov.x = acc[p*4+0]*inv; ov.y = acc[p*4+1]*inv;
    ov.z = acc[p*4+2]*inv; ov.w = acc[p*4+3]*inv;
    *(float4*)&op[p * 4] = ov;
  }
}

// ---------------------------------------------------------------------------
// out = LN(a + bvec) * w + bb
// ---------------------------------------------------------------------------
__global__ __launch_bounds__(256) void add_ln_k(
    const float* __restrict__ a, const float* __restrict__ bvec,
    const float* __restrict__ w, const float* __restrict__ bb,
    float* __restrict__ out)
{
  const int tid = threadIdx.x;
  const int wave = tid >> 6, lane = tid & 63;
  const size_t row = (size_t)blockIdx.x * 4 + wave;
  const float* pa = a + row * 128;
  const float* pb = bvec + row * 128;
  float v0 = pa[lane] + pb[lane];
  float v1 = pa[lane + 64] + pb[lane + 64];
  float s1 = v0 + v1, s2 = v0 * v0 + v1 * v1;
#pragma unroll
  for (int off = 32; off; off >>= 1) {
    s1 += __shfl_down(s1, off);
    s2 += __shfl_down(s2, off);
  }
  s1 = __shfl(s1, 0); s2 = __shfl(s2, 0);
  const float mean = s1 * (1.f / 128.f);
  const float var = s2 * (1.f / 128.f) - mean * mean;
  const float rs = rsqrtf(var + EPSV);
  out[row * 128 + lane]      = (v0 - mean) * rs * w[lane] + bb[lane];
  out[row * 128 + lane + 64] = (v1 - mean) * rs * w[lane + 64] + bb[lane + 64];
}

// ---------------------------------------------------------------------------
// Depthwise causal conv (DC=4) + SiLU
// ---------------------------------------------------------------------------
__global__ __launch_bounds__(256) void conv_silu_k(
    const float* __restrict__ xz, const float* __restrict__ cw,
    const float* __restrict__ cb, float* __restrict__ out)
{
  const int idx = blockIdx.x * 256 + threadIdx.x;
  const int di = idx & 1023;
  const int m = idx >> 10;
  const int t = m & (TT - 1);
  float acc = cb[di];
#pragma unroll
  for (int k = 0; k < 4; k++) {
    int tt = t + k - 3;
    if (tt >= 0) acc += xz[(size_t)(m + k - 3) * 2048 + di] * cw[di * 4 + k];
  }
  out[(size_t)m * 1024 + di] = acc / (1.f + __expf(-acc));
}

// ---------------------------------------------------------------------------
// Chunked selective scan.
// Phase A: per (b, di, chunk) local scan with h=0; emit P=prod(dA), S=local h.
// grid (16 di-slices * NCH, B), block 64.
// ---------------------------------------------------------------------------
__global__ __launch_bounds__(64) void scan_partial_k(
    const float* __restrict__ dt,    // (M,1024)
    const float* __restrict__ dbc,   // (M,64)
    const float* __restrict__ xi,    // (M,1024)
    const float* __restrict__ Alog,  // (1024,16)
    float* __restrict__ Pb, float* __restrict__ Sb)
{
  const int slice = blockIdx.x & 15;
  const int c = blockIdx.x >> 4;
  const int b = blockIdx.y;
  const int di = slice * 64 + threadIdx.x;

  float A[NSTATE];
#pragma unroll
  for (int n = 0; n < NSTATE; n++) A[n] = -__expf(Alog[di * NSTATE + n]);
  float h[NSTATE], P[NSTATE];
#pragma unroll
  for (int n = 0; n < NSTATE; n++) { h[n] = 0.f; P[n] = 1.f; }

  const size_t m0 = (size_t)b * TT + (size_t)c * CHUNK;
  for (int t = 0; t < CHUNK; t++) {
    const size_t m = m0 + t;
    const float dtv = dt[m * 1024 + di];
    const float xv  = xi[m * 1024 + di];
    const float dtx = dtv * xv;
#pragma unroll
    for (int n = 0; n < NSTATE; n++) {
      const float Bv = dbc[m * 64 + 32 + n];
      const float dA = __expf(dtv * A[n]);
      h[n] = h[n] * dA + dtx * Bv;
      P[n] *= dA;
    }
  }
  const size_t base = (((size_t)b * NCH + c) * NSTATE) * 1024 + di;
#pragma unroll
  for (int n = 0; n < NSTATE; n++) {
    Pb[base + (size_t)n * 1024] = P[n];
    Sb[base + (size_t)n * 1024] = h[n];
  }
}

// ---------------------------------------------------------------------------
// Phase B: sequential chunk fix-up per (b, di). Writes h_in per chunk into Pb.
// grid 32 blocks x 256.
// ---------------------------------------------------------------------------
__global__ __launch_bounds__(256) void scan_fix_k(
    float* __restrict__ Pb, const float* __restrict__ Sb)
{
  const int idx = blockIdx.x * 256 + threadIdx.x;   // b*1024 + di
  const int b = idx >> 10;
  const int di = idx & 1023;
  float h[NSTATE];
#pragma unroll
  for (int n = 0; n < NSTATE; n++) h[n] = 0.f;
  for (int c = 0; c < NCH; c++) {
    const size_t base = (((size_t)b * NCH + c) * NSTATE) * 1024 + di;
    float P[NSTATE], S[NSTATE];
#pragma unroll
    for (int n = 0; n < NSTATE; n++) {
      P[n] = Pb[base + (size_t)n * 1024];
      S[n] = Sb[base + (size_t)n * 1024];
    }
#pragma unroll
    for (int n = 0; n < NSTATE; n++) {
      Pb[base + (size_t)n * 1024] = h[n];        // h_in for chunk c
      h[n] = P[n] * h[n] + S[n];
    }
  }
}

// ---------------------------------------------------------------------------
// Phase C: re-run each chunk from correct h_in; y = dot(h,C) + D*x; *= silu(z).
// grid (16*NCH, B), block 64.
// ---------------------------------------------------------------------------
__global__ __launch_bounds__(64) void scan_final_k(
    const float* __restrict__ dt,
    const float* __restrict__ dbc,
    const float* __restrict__ xi,
    const float* __restrict__ xz,    // (M,2048) — z at +1024
    const float* __restrict__ Alog,
    const float* __restrict__ Dp,
    const float* __restrict__ Hin,   // == Pb
    float* __restrict__ Y)
{
  const int slice = blockIdx.x & 15;
  const int c = blockIdx.x >> 4;
  const int b = blockIdx.y;
  const int di = slice * 64 + threadIdx.x;

  float A[NSTATE];
#pragma unroll
  for (int n = 0; n < NSTATE; n++) A[n] = -__expf(Alog[di * NSTATE + n]);
  const float Dv = Dp[di];
  float h[NSTATE];
  const size_t hbase = (((size_t)b * NCH + c) * NSTATE) * 1024 + di;
#pragma unroll
  for (int n = 0; n < NSTATE; n++) h[n] = Hin[hbase + (size_t)n * 1024];

  const size_t m0 = (size_t)b * TT + (size_t)c * CHUNK;
  for (int t = 0; t < CHUNK; t++) {
    const size_t m = m0 + t;
    const float dtv = dt[m * 1024 + di];
    const float xv  = xi[m * 1024 + di];
    const float zv  = xz[m * 2048 + 1024 + di];
    const float dtx = dtv * xv;
    float y = 0.f;
#pragma unroll
    for (int n = 0; n < NSTATE; n++) {
      const float Bv = dbc[m * 64 + 32 + n];
      const float Cv = dbc[m * 64 + 48 + n];
      const float dA = __expf(dtv * A[n]);
      h[n] = h[n] * dA + dtx * Bv;
      y += h[n] * Cv;
    }
    y += Dv * xv;
    y *= zv / (1.f + __expf(-zv));
    Y[m * 1024 + di] = y;
  }
}

// ---------------------------------------------------------------------------
extern "C" void kernel_launch(void* const* d_in, const int* in_sizes, int n_in,
                              void* d_out, int out_size, void* d_ws, size_t ws_size,
                              hipStream_t stream)
{
  const float* emb      = (const float*)d_in[0];
  const float* t_wqkv   = (const float*)d_in[1];
  const float* t_bqkv   = (const float*)d_in[2];
  const float* t_wo     = (const float*)d_in[3];
  const float* t_bo     = (const float*)d_in[4];
  const float* t_ln1w   = (const float*)d_in[5];
  const float* t_ln1b   = (const float*)d_in[6];
  const float* t_w1     = (const float*)d_in[7];
  const float* t_b1     = (const float*)d_in[8];
  const float* t_w2     = (const float*)d_in[9];
  const float* t_b2     = (const float*)d_in[10];
  const float* t_ln2w   = (const float*)d_in[11];
  const float* t_ln2b   = (const float*)d_in[12];
  const float* w_in     = (const float*)d_in[13];
  const float* b_in     = (const float*)d_in[14];
  const float* m_inproj = (const float*)d_in[15];
  const float* m_convw  = (const float*)d_in[16];
  const float* m_convb  = (const float*)d_in[17];
  const float* m_xproj  = (const float*)d_in[18];
  const float* m_dtw    = (const float*)d_in[19];
  const float* m_dtb    = (const float*)d_in[20];
  const float* m_Alog   = (const float*)d_in[21];
  const float* m_D      = (const float*)d_in[22];
  const float* m_outproj= (const float*)d_in[23];
  const float* w_out    = (const float*)d_in[24];
  const float* b_out    = (const float*)d_in[25];

  float* ws = (float*)d_ws;
  float* X0   = ws;                               // M*512
  float* X1   = X0 + (size_t)MM * 512;            // M*512
  float* Abuf = X1 + (size_t)MM * 512;            // M*2048 (qkv | ff1 | xz)
  float* Bf   = Abuf + (size_t)MM * 2048;         // M*1024 (xi_act)
  float* Cf   = Bf + (size_t)MM * 1024;           // M*1024 (wo-out | ff2 | dt)
  float* Yb   = Cf + (size_t)MM * 1024;           // M*1024 (attn o | scan y)
  float* Db   = Yb + (size_t)MM * 1024;           // M*64   (dbc)

  dim3 blk(256);
  auto gemm = [&](const float* A, int lda, const float* W, const float* bias,
                  float* C, int N, int K, int act) {
    if (N >= 512 && (K % 8) == 0) {
      dim3 g(N / 128, MM / 128);
      hipLaunchKernelGGL(gemm128_k, g, blk, 0, stream, A, lda, W, bias, C, N, K, act);
    } else {
      dim3 g(N / 64, MM / 64);
      hipLaunchKernelGGL(gemm_k, g, blk, 0, stream, A, lda, W, bias, C, N, K, act);
    }
  };

  const float* x = emb;
  for (int l = 0; l < NTT; l++) {
    gemm(x, 128, t_wqkv + (size_t)l * 384 * 128, t_bqkv + l * 384, Abuf, 384, 128, 0);
    hipLaunchKernelGGL(attn_k, dim3(TT / 256, HB * 8), blk, 0, stream, Abuf, Yb);
    gemm(Yb, 128, t_wo + (size_t)l * 128 * 128, t_bo + l * 128, Cf, 128, 128, 0);
    hipLaunchKernelGGL(add_ln_k, dim3(MM / 4), blk, 0, stream,
                       x, Cf, t_ln1w + l * 128, t_ln1b + l * 128, X0);
    gemm(X0, 128, t_w1 + (size_t)l * 2048 * 128, t_b1 + l * 2048, Abuf, 2048, 128, 1);
    gemm(Abuf, 2048, t_w2 + (size_t)l * 128 * 2048, t_b2 + l * 128, Cf, 128, 2048, 0);
    hipLaunchKernelGGL(add_ln_k, dim3(MM / 4), blk, 0, stream,
                       X0, Cf, t_ln2w + l * 128, t_ln2b + l * 128, X0);
    x = X0;
  }

  gemm(X0, 128, w_in, b_in, X1, 512, 128, 0);

  float* xc = X1;
  float* xo = X0;
  for (int l = 0; l < NMM; l++) {
    gemm(xc, 512, m_inproj + (size_t)l * 2048 * 512, nullptr, Abuf, 2048, 512, 0);
    hipLaunchKernelGGL(conv_silu_k, dim3(MM * 1024 / 256), blk, 0, stream,
                       Abuf, m_convw + (size_t)l * 1024 * 4, m_convb + l * 1024, Bf);
    gemm(Bf, 1024, m_xproj + (size_t)l * 64 * 1024, nullptr, Db, 64, 1024, 0);
    gemm(Db, 64, m_dtw + (size_t)l * 1024 * 32, m_dtb + l * 1024, Cf, 1024, 32, 2);

    // chunked scan; P/S/Hin overlaid on the dead ping-pong buffer xo (16 MB)
    float* Pb = xo;
    float* Sb = xo + (size_t)HB * NCH * NSTATE * 1024;   // +2M floats
    hipLaunchKernelGGL(scan_partial_k, dim3(16 * NCH, HB), dim3(64), 0, stream,
                       Cf, Db, Bf, m_Alog + (size_t)l * 1024 * 16, Pb, Sb);
    hipLaunchKernelGGL(scan_fix_k, dim3(MM / 1024 * 4), blk, 0, stream, Pb, Sb);
    hipLaunchKernelGGL(scan_final_k, dim3(16 * NCH, HB), dim3(64), 0, stream,
                       Cf, Db, Bf, Abuf,
                       m_Alog + (size_t)l * 1024 * 16, m_D + l * 1024, Pb, Yb);

    gemm(Yb, 1024, m_outproj + (size_t)l * 512 * 1024, nullptr, xo, 512, 1024, 0);
    float* tmp = xc; xc = xo; xo = tmp;
  }

  gemm(xc, 512, w_out, b_out, (float*)d_out, 128, 512, 0);
}

// Round 3
// 6657.160 us; speedup vs baseline: 1.6397x; 1.0917x over previous
//
#include <hip/hip_runtime.h>
#include <math.h>

#define HB 8
#define TT 1024
#define EE 128
#define DD 512
#define DDI 1024
#define NSTATE 16
#define NTT 6
#define NMM 8
#define FFF 2048
#define MM (HB*TT)   /* 8192 rows */
#define EPSV 1e-5f
#define CHUNK 64
#define NCH (TT/CHUNK)   /* 16 */
#define NSEG 8           /* attention key segments */
#define SEGK (TT/NSEG)   /* 128 keys per segment */

// ---------------------------------------------------------------------------
// Generic fp32 GEMM: C(M,N) = act( A(M,K; lda) @ W(N,K)^T + bias )
// act: 0 none, 1 relu, 2 softplus.  Tiles 64x64, 256 thr, 4x4/thr, K-step 16.
// ---------------------------------------------------------------------------
__global__ __launch_bounds__(256) void gemm_k(
    const float* __restrict__ A, int lda,
    const float* __restrict__ W,
    const float* __restrict__ bias,
    float* __restrict__ C,
    int N, int K, int act)
{
  __shared__ __align__(16) float As[16][64];
  __shared__ __align__(16) float Bs[16][64];
  const int tid = threadIdx.x;
  const int m0 = blockIdx.y * 64;
  const int n0 = blockIdx.x * 64;
  const int tr = tid >> 4;
  const int tc = tid & 15;
  const int lr = tid >> 2;
  const int lk = (tid & 3) << 2;

  float acc[4][4];
#pragma unroll
  for (int i = 0; i < 4; i++)
#pragma unroll
    for (int j = 0; j < 4; j++) acc[i][j] = 0.f;

  for (int k0 = 0; k0 < K; k0 += 16) {
    float4 av = *(const float4*)&A[(size_t)(m0 + lr) * lda + k0 + lk];
    float4 wv = *(const float4*)&W[(size_t)(n0 + lr) * K + k0 + lk];
    __syncthreads();
    As[lk + 0][lr] = av.x; As[lk + 1][lr] = av.y;
    As[lk + 2][lr] = av.z; As[lk + 3][lr] = av.w;
    Bs[lk + 0][lr] = wv.x; Bs[lk + 1][lr] = wv.y;
    Bs[lk + 2][lr] = wv.z; Bs[lk + 3][lr] = wv.w;
    __syncthreads();
#pragma unroll
    for (int kk = 0; kk < 16; ++kk) {
      float4 a = *(const float4*)&As[kk][tr * 4];
      float4 b = *(const float4*)&Bs[kk][tc * 4];
      float av4[4] = {a.x, a.y, a.z, a.w};
      float bv4[4] = {b.x, b.y, b.z, b.w};
#pragma unroll
      for (int i = 0; i < 4; i++)
#pragma unroll
        for (int j = 0; j < 4; j++) acc[i][j] += av4[i] * bv4[j];
    }
  }

#pragma unroll
  for (int i = 0; i < 4; i++) {
    const int m = m0 + tr * 4 + i;
    float4 o;
    float* po = (float*)&o;
#pragma unroll
    for (int j = 0; j < 4; j++) {
      float v = acc[i][j];
      const int n = n0 + tc * 4 + j;
      if (bias) v += bias[n];
      if (act == 1) v = fmaxf(v, 0.f);
      else if (act == 2) v = fmaxf(v, 0.f) + log1pf(__expf(-fabsf(v)));
      po[j] = v;
    }
    *(float4*)&C[(size_t)m * N + n0 + tc * 4] = o;
  }
}

// ---------------------------------------------------------------------------
// Big-tile fp32 GEMM: 128x128 tile, 256 thr, 8x8/thr (split 4+4), K-step 8.
// ---------------------------------------------------------------------------
__global__ __launch_bounds__(256) void gemm128_k(
    const float* __restrict__ A, int lda,
    const float* __restrict__ W,
    const float* __restrict__ bias,
    float* __restrict__ C,
    int N, int K, int act)
{
  __shared__ __align__(16) float As[8][128];
  __shared__ __align__(16) float Bs[8][128];
  const int tid = threadIdx.x;
  const int m0 = blockIdx.y * 128;
  const int n0 = blockIdx.x * 128;
  const int lr = tid >> 1;
  const int lk = (tid & 1) * 4;
  const int tr = tid >> 4;
  const int tc = tid & 15;
  const int r0 = tr * 4;
  const int c0 = tc * 4;

  float acc[8][8];
#pragma unroll
  for (int i = 0; i < 8; i++)
#pragma unroll
    for (int j = 0; j < 8; j++) acc[i][j] = 0.f;

  for (int k0 = 0; k0 < K; k0 += 8) {
    float4 av = *(const float4*)&A[(size_t)(m0 + lr) * lda + k0 + lk];
    float4 wv = *(const float4*)&W[(size_t)(n0 + lr) * K + k0 + lk];
    __syncthreads();
    As[lk + 0][lr] = av.x; As[lk + 1][lr] = av.y;
    As[lk + 2][lr] = av.z; As[lk + 3][lr] = av.w;
    Bs[lk + 0][lr] = wv.x; Bs[lk + 1][lr] = wv.y;
    Bs[lk + 2][lr] = wv.z; Bs[lk + 3][lr] = wv.w;
    __syncthreads();
#pragma unroll
    for (int kk = 0; kk < 8; ++kk) {
      float4 alo = *(const float4*)&As[kk][r0];
      float4 ahi = *(const float4*)&As[kk][64 + r0];
      float4 blo = *(const float4*)&Bs[kk][c0];
      float4 bhi = *(const float4*)&Bs[kk][64 + c0];
      float a8[8] = {alo.x, alo.y, alo.z, alo.w, ahi.x, ahi.y, ahi.z, ahi.w};
      float b8[8] = {blo.x, blo.y, blo.z, blo.w, bhi.x, bhi.y, bhi.z, bhi.w};
#pragma unroll
      for (int i = 0; i < 8; i++)
#pragma unroll
        for (int j = 0; j < 8; j++) acc[i][j] += a8[i] * b8[j];
    }
  }

#pragma unroll
  for (int ih = 0; ih < 2; ih++) {
#pragma unroll
    for (int i = 0; i < 4; i++) {
      const int m = m0 + ih * 64 + r0 + i;
#pragma unroll
      for (int jh = 0; jh < 2; jh++) {
        const int nb = n0 + jh * 64 + c0;
        float4 o;
        float* po = (float*)&o;
#pragma unroll
        for (int j = 0; j < 4; j++) {
          float v = acc[ih * 4 + i][jh * 4 + j];
          if (bias) v += bias[nb + j];
          if (act == 1) v = fmaxf(v, 0.f);
          else if (act == 2) v = fmaxf(v, 0.f) + log1pf(__expf(-fabsf(v)));
          po[j] = v;
        }
        *(float4*)&C[(size_t)m * N + nb] = o;
      }
    }
  }
}

// ---------------------------------------------------------------------------
// Attention phase 1: online-softmax partials over one key segment.
// qkv (M,384) rows [q|k|v], head dim 16, scale 0.25 (folded into q).
// Each thread owns 2 queries; block = 512 queries x 1 segment (128 keys).
// grid (2 qt * 8 seg, B*H), block 256.
// Pacc layout [bh*8+seg][16][1024(t)]; Pml layout [bh*8+seg][2][1024(t)].
// ---------------------------------------------------------------------------
__global__ __launch_bounds__(256, 4) void attn_part_k(
    const float* __restrict__ qkv,
    float* __restrict__ Pacc, float* __restrict__ Pml)
{
  __shared__ __align__(16) float Ks[SEGK * 16];
  __shared__ __align__(16) float Vs[SEGK * 16];
  const int tid = threadIdx.x;
  const int qt  = blockIdx.x & 1;
  const int seg = blockIdx.x >> 1;
  const int bh = blockIdx.y;
  const int b = bh >> 3;
  const int h = bh & 7;
  const int t0 = qt * 512 + tid;
  const int t1 = t0 + 256;

  float q0[16], q1[16];
  {
    const float* qp0 = qkv + ((size_t)(b * TT + t0)) * 384 + h * 16;
    const float* qp1 = qkv + ((size_t)(b * TT + t1)) * 384 + h * 16;
#pragma unroll
    for (int p = 0; p < 4; p++) {
      float4 a = *(const float4*)&qp0[p * 4];
      q0[p*4+0] = a.x * 0.25f; q0[p*4+1] = a.y * 0.25f;
      q0[p*4+2] = a.z * 0.25f; q0[p*4+3] = a.w * 0.25f;
      float4 c = *(const float4*)&qp1[p * 4];
      q1[p*4+0] = c.x * 0.25f; q1[p*4+1] = c.y * 0.25f;
      q1[p*4+2] = c.z * 0.25f; q1[p*4+3] = c.w * 0.25f;
    }
  }

  // stage this segment's K and V (128 rows x 16)
  const size_t baseK = ((size_t)(b * TT + seg * SEGK)) * 384 + 128 + h * 16;
  for (int idx = tid; idx < 512; idx += 256) {
    int row = idx >> 2, part = idx & 3;
    *(float4*)&Ks[row * 16 + part * 4] =
        *(const float4*)&qkv[baseK + (size_t)row * 384 + part * 4];
    *(float4*)&Vs[row * 16 + part * 4] =
        *(const float4*)&qkv[baseK + 128 + (size_t)row * 384 + part * 4];
  }
  __syncthreads();

  float m0 = -1e30f, l0 = 0.f, m1 = -1e30f, l1 = 0.f;
  float acc0[16], acc1[16];
#pragma unroll
  for (int d = 0; d < 16; d++) { acc0[d] = 0.f; acc1[d] = 0.f; }

  for (int j = 0; j < SEGK; j++) {
    float4 k0 = *(const float4*)&Ks[j * 16 + 0];
    float4 k1 = *(const float4*)&Ks[j * 16 + 4];
    float4 k2 = *(const float4*)&Ks[j * 16 + 8];
    float4 k3 = *(const float4*)&Ks[j * 16 + 12];
    float s0 = q0[0]*k0.x + q0[1]*k0.y + q0[2]*k0.z + q0[3]*k0.w
             + q0[4]*k1.x + q0[5]*k1.y + q0[6]*k1.z + q0[7]*k1.w
             + q0[8]*k2.x + q0[9]*k2.y + q0[10]*k2.z + q0[11]*k2.w
             + q0[12]*k3.x + q0[13]*k3.y + q0[14]*k3.z + q0[15]*k3.w;
    float s1 = q1[0]*k0.x + q1[1]*k0.y + q1[2]*k0.z + q1[3]*k0.w
             + q1[4]*k1.x + q1[5]*k1.y + q1[6]*k1.z + q1[7]*k1.w
             + q1[8]*k2.x + q1[9]*k2.y + q1[10]*k2.z + q1[11]*k2.w
             + q1[12]*k3.x + q1[13]*k3.y + q1[14]*k3.z + q1[15]*k3.w;
    if (s0 > m0) {
      float alpha = __expf(m0 - s0);
      l0 *= alpha;
#pragma unroll
      for (int d = 0; d < 16; d++) acc0[d] *= alpha;
      m0 = s0;
    }
    if (s1 > m1) {
      float alpha = __expf(m1 - s1);
      l1 *= alpha;
#pragma unroll
      for (int d = 0; d < 16; d++) acc1[d] *= alpha;
      m1 = s1;
    }
    float p0 = __expf(s0 - m0);
    float p1 = __expf(s1 - m1);
    l0 += p0; l1 += p1;
    float4 v0 = *(const float4*)&Vs[j * 16 + 0];
    float4 v1 = *(const float4*)&Vs[j * 16 + 4];
    float4 v2 = *(const float4*)&Vs[j * 16 + 8];
    float4 v3 = *(const float4*)&Vs[j * 16 + 12];
    acc0[0] += p0*v0.x; acc0[1] += p0*v0.y; acc0[2] += p0*v0.z; acc0[3] += p0*v0.w;
    acc0[4] += p0*v1.x; acc0[5] += p0*v1.y; acc0[6] += p0*v1.z; acc0[7] += p0*v1.w;
    acc0[8] += p0*v2.x; acc0[9] += p0*v2.y; acc0[10]+= p0*v2.z; acc0[11]+= p0*v2.w;
    acc0[12]+= p0*v3.x; acc0[13]+= p0*v3.y; acc0[14]+= p0*v3.z; acc0[15]+= p0*v3.w;
    acc1[0] += p1*v0.x; acc1[1] += p1*v0.y; acc1[2] += p1*v0.z; acc1[3] += p1*v0.w;
    acc1[4] += p1*v1.x; acc1[5] += p1*v1.y; acc1[6] += p1*v1.z; acc1[7] += p1*v1.w;
    acc1[8] += p1*v2.x; acc1[9] += p1*v2.y; acc1[10]+= p1*v2.z; acc1[11]+= p1*v2.w;
    acc1[12]+= p1*v3.x; acc1[13]+= p1*v3.y; acc1[14]+= p1*v3.z; acc1[15]+= p1*v3.w;
  }

  const size_t ps = (size_t)bh * NSEG + seg;
  float* pm = Pml + ps * 2048;
  pm[t0] = m0; pm[t1] = m1;
  pm[1024 + t0] = l0; pm[1024 + t1] = l1;
  float* pa = Pacc + ps * 16 * 1024;
#pragma unroll
  for (int d = 0; d < 16; d++) {
    pa[(size_t)d * 1024 + t0] = acc0[d];
    pa[(size_t)d * 1024 + t1] = acc1[d];
  }
}

// ---------------------------------------------------------------------------
// Attention phase 2: merge 8 segment partials -> o (M,128).
// thread per (bh, t). grid 256 x 256.
// ---------------------------------------------------------------------------
__global__ __launch_bounds__(256) void attn_comb_k(
    const float* __restrict__ Pacc, const float* __restrict__ Pml,
    float* __restrict__ o)
{
  const int idx = blockIdx.x * 256 + threadIdx.x;   // bh*1024 + t
  const int bh = idx >> 10;
  const int t = idx & 1023;
  const int b = bh >> 3;
  const int h = bh & 7;

  float ms[NSEG], ls[NSEG];
  float mstar = -1e30f;
#pragma unroll
  for (int s = 0; s < NSEG; s++) {
    const float* pm = Pml + ((size_t)bh * NSEG + s) * 2048;
    ms[s] = pm[t];
    ls[s] = pm[1024 + t];
    mstar = fmaxf(mstar, ms[s]);
  }
  float w[NSEG];
  float lstar = 0.f;
#pragma unroll
  for (int s = 0; s < NSEG; s++) {
    w[s] = __expf(ms[s] - mstar);
    lstar += w[s] * ls[s];
  }
  const float inv = 1.f / lstar;

  float out[16];
#pragma unroll
  for (int d = 0; d < 16; d++) out[d] = 0.f;
#pragma unroll
  for (int s = 0; s < NSEG; s++) {
    const float* pa = Pacc + ((size_t)bh * NSEG + s) * 16 * 1024;
#pragma unroll
    for (int d = 0; d < 16; d++) out[d] += w[s] * pa[(size_t)d * 1024 + t];
  }
  float* op = o + ((size_t)(b * TT + t)) * 128 + h * 16;
#pragma unroll
  for (int p = 0; p < 4; p++) {
    float4 ov;
    ov.x = out[p*4+0] * inv; ov.y = out[p*4+1] * inv;
    ov.z = out[p*4+2] * inv; ov.w = out[p*4+3] * inv;
    *(float4*)&op[p * 4] = ov;
  }
}

// ---------------------------------------------------------------------------
// out = LN(a + bvec) * w + bb
// ---------------------------------------------------------------------------
__global__ __launch_bounds__(256) void add_ln_k(
    const float* __restrict__ a, const float* __restrict__ bvec,
    const float* __restrict__ w, const float* __restrict__ bb,
    float* __restrict__ out)
{
  const int tid = threadIdx.x;
  const int wave = tid >> 6, lane = tid & 63;
  const size_t row = (size_t)blockIdx.x * 4 + wave;
  const float* pa = a + row * 128;
  const float* pb = bvec + row * 128;
  float v0 = pa[lane] + pb[lane];
  float v1 = pa[lane + 64] + pb[lane + 64];
  float s1 = v0 + v1, s2 = v0 * v0 + v1 * v1;
#pragma unroll
  for (int off = 32; off; off >>= 1) {
    s1 += __shfl_down(s1, off);
    s2 += __shfl_down(s2, off);
  }
  s1 = __shfl(s1, 0); s2 = __shfl(s2, 0);
  const float mean = s1 * (1.f / 128.f);
  const float var = s2 * (1.f / 128.f) - mean * mean;
  const float rs = rsqrtf(var + EPSV);
  out[row * 128 + lane]      = (v0 - mean) * rs * w[lane] + bb[lane];
  out[row * 128 + lane + 64] = (v1 - mean) * rs * w[lane + 64] + bb[lane + 64];
}

// ---------------------------------------------------------------------------
// Depthwise causal conv (DC=4) + SiLU
// ---------------------------------------------------------------------------
__global__ __launch_bounds__(256) void conv_silu_k(
    const float* __restrict__ xz, const float* __restrict__ cw,
    const float* __restrict__ cb, float* __restrict__ out)
{
  const int idx = blockIdx.x * 256 + threadIdx.x;
  const int di = idx & 1023;
  const int m = idx >> 10;
  const int t = m & (TT - 1);
  float acc = cb[di];
#pragma unroll
  for (int k = 0; k < 4; k++) {
    int tt = t + k - 3;
    if (tt >= 0) acc += xz[(size_t)(m + k - 3) * 2048 + di] * cw[di * 4 + k];
  }
  out[(size_t)m * 1024 + di] = acc / (1.f + __expf(-acc));
}

// ---------------------------------------------------------------------------
// Chunked selective scan, phase A: local scan, emit P=prod(dA), S=local h.
// ---------------------------------------------------------------------------
__global__ __launch_bounds__(64) void scan_partial_k(
    const float* __restrict__ dt,
    const float* __restrict__ dbc,
    const float* __restrict__ xi,
    const float* __restrict__ Alog,
    float* __restrict__ Pb, float* __restrict__ Sb)
{
  const int slice = blockIdx.x & 15;
  const int c = blockIdx.x >> 4;
  const int b = blockIdx.y;
  const int di = slice * 64 + threadIdx.x;

  float A[NSTATE];
#pragma unroll
  for (int n = 0; n < NSTATE; n++) A[n] = -__expf(Alog[di * NSTATE + n]);
  float h[NSTATE], P[NSTATE];
#pragma unroll
  for (int n = 0; n < NSTATE; n++) { h[n] = 0.f; P[n] = 1.f; }

  const size_t m0 = (size_t)b * TT + (size_t)c * CHUNK;
  for (int t = 0; t < CHUNK; t++) {
    const size_t m = m0 + t;
    const float dtv = dt[m * 1024 + di];
    const float xv  = xi[m * 1024 + di];
    const float dtx = dtv * xv;
#pragma unroll
    for (int n = 0; n < NSTATE; n++) {
      const float Bv = dbc[m * 64 + 32 + n];
      const float dA = __expf(dtv * A[n]);
      h[n] = h[n] * dA + dtx * Bv;
      P[n] *= dA;
    }
  }
  const size_t base = (((size_t)b * NCH + c) * NSTATE) * 1024 + di;
#pragma unroll
  for (int n = 0; n < NSTATE; n++) {
    Pb[base + (size_t)n * 1024] = P[n];
    Sb[base + (size_t)n * 1024] = h[n];
  }
}

// ---------------------------------------------------------------------------
// Phase B: sequential chunk fix-up per (b, di). Writes h_in per chunk into Pb.
// ---------------------------------------------------------------------------
__global__ __launch_bounds__(256) void scan_fix_k(
    float* __restrict__ Pb, const float* __restrict__ Sb)
{
  const int idx = blockIdx.x * 256 + threadIdx.x;
  const int b = idx >> 10;
  const int di = idx & 1023;
  float h[NSTATE];
#pragma unroll
  for (int n = 0; n < NSTATE; n++) h[n] = 0.f;
  for (int c = 0; c < NCH; c++) {
    const size_t base = (((size_t)b * NCH + c) * NSTATE) * 1024 + di;
    float P[NSTATE], S[NSTATE];
#pragma unroll
    for (int n = 0; n < NSTATE; n++) {
      P[n] = Pb[base + (size_t)n * 1024];
      S[n] = Sb[base + (size_t)n * 1024];
    }
#pragma unroll
    for (int n = 0; n < NSTATE; n++) {
      Pb[base + (size_t)n * 1024] = h[n];
      h[n] = P[n] * h[n] + S[n];
    }
  }
}

// ---------------------------------------------------------------------------
// Phase C: re-run each chunk from h_in; y = dot(h,C) + D*x; *= silu(z).
// ---------------------------------------------------------------------------
__global__ __launch_bounds__(64) void scan_final_k(
    const float* __restrict__ dt,
    const float* __restrict__ dbc,
    const float* __restrict__ xi,
    const float* __restrict__ xz,
    const float* __restrict__ Alog,
    const float* __restrict__ Dp,
    const float* __restrict__ Hin,
    float* __restrict__ Y)
{
  const int slice = blockIdx.x & 15;
  const int c = blockIdx.x >> 4;
  const int b = blockIdx.y;
  const int di = slice * 64 + threadIdx.x;

  float A[NSTATE];
#pragma unroll
  for (int n = 0; n < NSTATE; n++) A[n] = -__expf(Alog[di * NSTATE + n]);
  const float Dv = Dp[di];
  float h[NSTATE];
  const size_t hbase = (((size_t)b * NCH + c) * NSTATE) * 1024 + di;
#pragma unroll
  for (int n = 0; n < NSTATE; n++) h[n] = Hin[hbase + (size_t)n * 1024];

  const size_t m0 = (size_t)b * TT + (size_t)c * CHUNK;
  for (int t = 0; t < CHUNK; t++) {
    const size_t m = m0 + t;
    const float dtv = dt[m * 1024 + di];
    const float xv  = xi[m * 1024 + di];
    const float zv  = xz[m * 2048 + 1024 + di];
    const float dtx = dtv * xv;
    float y = 0.f;
#pragma unroll
    for (int n = 0; n < NSTATE; n++) {
      const float Bv = dbc[m * 64 + 32 + n];
      const float Cv = dbc[m * 64 + 48 + n];
      const float dA = __expf(dtv * A[n]);
      h[n] = h[n] * dA + dtx * Bv;
      y += h[n] * Cv;
    }
    y += Dv * xv;
    y *= zv / (1.f + __expf(-zv));
    Y[m * 1024 + di] = y;
  }
}

// ---------------------------------------------------------------------------
extern "C" void kernel_launch(void* const* d_in, const int* in_sizes, int n_in,
                              void* d_out, int out_size, void* d_ws, size_t ws_size,
                              hipStream_t stream)
{
  const float* emb      = (const float*)d_in[0];
  const float* t_wqkv   = (const float*)d_in[1];
  const float* t_bqkv   = (const float*)d_in[2];
  const float* t_wo     = (const float*)d_in[3];
  const float* t_bo     = (const float*)d_in[4];
  const float* t_ln1w   = (const float*)d_in[5];
  const float* t_ln1b   = (const float*)d_in[6];
  const float* t_w1     = (const float*)d_in[7];
  const float* t_b1     = (const float*)d_in[8];
  const float* t_w2     = (const float*)d_in[9];
  const float* t_b2     = (const float*)d_in[10];
  const float* t_ln2w   = (const float*)d_in[11];
  const float* t_ln2b   = (const float*)d_in[12];
  const float* w_in     = (const float*)d_in[13];
  const float* b_in     = (const float*)d_in[14];
  const float* m_inproj = (const float*)d_in[15];
  const float* m_convw  = (const float*)d_in[16];
  const float* m_convb  = (const float*)d_in[17];
  const float* m_xproj  = (const float*)d_in[18];
  const float* m_dtw    = (const float*)d_in[19];
  const float* m_dtb    = (const float*)d_in[20];
  const float* m_Alog   = (const float*)d_in[21];
  const float* m_D      = (const float*)d_in[22];
  const float* m_outproj= (const float*)d_in[23];
  const float* w_out    = (const float*)d_in[24];
  const float* b_out    = (const float*)d_in[25];

  float* ws = (float*)d_ws;
  float* X0   = ws;                               // M*512
  float* X1   = X0 + (size_t)MM * 512;            // M*512
  float* Abuf = X1 + (size_t)MM * 512;            // M*2048 (qkv | ff1 | xz)
  float* Bf   = Abuf + (size_t)MM * 2048;         // M*1024 (xi_act)
  float* Cf   = Bf + (size_t)MM * 1024;           // M*1024 (wo-out | ff2 | dt | attn Pacc)
  float* Yb   = Cf + (size_t)MM * 1024;           // M*1024 (attn o | scan y)
  float* Db   = Yb + (size_t)MM * 1024;           // M*64   (dbc)
  float* Pml  = Db + (size_t)MM * 64;             // 64*8*2*1024 (attn m/l partials)

  dim3 blk(256);
  auto gemm = [&](const float* A, int lda, const float* W, const float* bias,
                  float* C, int N, int K, int act) {
    if (N >= 512 && (K % 8) == 0) {
      dim3 g(N / 128, MM / 128);
      hipLaunchKernelGGL(gemm128_k, g, blk, 0, stream, A, lda, W, bias, C, N, K, act);
    } else {
      dim3 g(N / 64, MM / 64);
      hipLaunchKernelGGL(gemm_k, g, blk, 0, stream, A, lda, W, bias, C, N, K, act);
    }
  };

  const float* x = emb;
  for (int l = 0; l < NTT; l++) {
    gemm(x, 128, t_wqkv + (size_t)l * 384 * 128, t_bqkv + l * 384, Abuf, 384, 128, 0);
    // attention: partials (Pacc in Cf, m/l in Pml) then combine into Yb
    hipLaunchKernelGGL(attn_part_k, dim3(2 * NSEG, HB * 8), blk, 0, stream,
                       Abuf, Cf, Pml);
    hipLaunchKernelGGL(attn_comb_k, dim3(HB * 8 * TT / 256), blk, 0, stream,
                       Cf, Pml, Yb);
    gemm(Yb, 128, t_wo + (size_t)l * 128 * 128, t_bo + l * 128, Cf, 128, 128, 0);
    hipLaunchKernelGGL(add_ln_k, dim3(MM / 4), blk, 0, stream,
                       x, Cf, t_ln1w + l * 128, t_ln1b + l * 128, X0);
    gemm(X0, 128, t_w1 + (size_t)l * 2048 * 128, t_b1 + l * 2048, Abuf, 2048, 128, 1);
    gemm(Abuf, 2048, t_w2 + (size_t)l * 128 * 2048, t_b2 + l * 128, Cf, 128, 2048, 0);
    hipLaunchKernelGGL(add_ln_k, dim3(MM / 4), blk, 0, stream,
                       X0, Cf, t_ln2w + l * 128, t_ln2b + l * 128, X0);
    x = X0;
  }

  gemm(X0, 128, w_in, b_in, X1, 512, 128, 0);

  float* xc = X1;
  float* xo = X0;
  for (int l = 0; l < NMM; l++) {
    gemm(xc, 512, m_inproj + (size_t)l * 2048 * 512, nullptr, Abuf, 2048, 512, 0);
    hipLaunchKernelGGL(conv_silu_k, dim3(MM * 1024 / 256), blk, 0, stream,
                       Abuf, m_convw + (size_t)l * 1024 * 4, m_convb + l * 1024, Bf);
    gemm(Bf, 1024, m_xproj + (size_t)l * 64 * 1024, nullptr, Db, 64, 1024, 0);
    gemm(Db, 64, m_dtw + (size_t)l * 1024 * 32, m_dtb + l * 1024, Cf, 1024, 32, 2);

    float* Pb = xo;
    float* Sb = xo + (size_t)HB * NCH * NSTATE * 1024;
    hipLaunchKernelGGL(scan_partial_k, dim3(16 * NCH, HB), dim3(64), 0, stream,
                       Cf, Db, Bf, m_Alog + (size_t)l * 1024 * 16, Pb, Sb);
    hipLaunchKernelGGL(scan_fix_k, dim3(MM / 1024 * 4), blk, 0, stream, Pb, Sb);
    hipLaunchKernelGGL(scan_final_k, dim3(16 * NCH, HB), dim3(64), 0, stream,
                       Cf, Db, Bf, Abuf,
                       m_Alog + (size_t)l * 1024 * 16, m_D + l * 1024, Pb, Yb);

    gemm(Yb, 1024, m_outproj + (size_t)l * 512 * 1024, nullptr, xo, 512, 1024, 0);
    float* tmp = xc; xc = xo; xo = tmp;
  }

  gemm(xc, 512, w_out, b_out, (float*)d_out, 128, 512, 0);
}

// Round 4
// 4817.476 us; speedup vs baseline: 2.2659x; 1.3819x over previous
//
#include <hip/hip_runtime.h>
#include <math.h>

#define HB 8
#define TT 1024
#define NSTATE 16
#define NTT 6
#define NMM 8
#define MM (HB*TT)   /* 8192 rows */
#define EPSV 1e-5f
#define CHUNK 64
#define NCH (TT/CHUNK)   /* 16 */
#define NSEG 8           /* attention key segments */
#define SEGK (TT/NSEG)   /* 128 keys per segment */
#define LSTR 72          /* LDS row stride in halves: [32 hi|32 lo|8 pad] */

typedef _Float16 f16x8 __attribute__((ext_vector_type(8)));
typedef float f32x4_t __attribute__((ext_vector_type(4)));

// ---------------------------------------------------------------------------
// fp16x3 split-precision MFMA GEMM: C(M,N) = act( A(M,K; lda) @ W(N,K)^T + b )
// act: 0 none, 1 relu, 2 softplus. Requires N%128==0, K%32==0, M%128==0.
// 128x128 tile, 256 threads (2x2 waves of 64x64), BK=32.
// ---------------------------------------------------------------------------
__global__ __launch_bounds__(256) void gemm_mfma_k(
    const float* __restrict__ A, int lda,
    const float* __restrict__ W,
    const float* __restrict__ bias,
    float* __restrict__ C,
    int N, int K, int act)
{
  __shared__ _Float16 As[128 * LSTR];
  __shared__ _Float16 Bs[128 * LSTR];
  const int tid = threadIdx.x;
  const int m0 = blockIdx.y * 128;
  const int n0 = blockIdx.x * 128;
  const int lr = tid >> 1;          // staging row 0..127
  const int lh = tid & 1;           // staging col half (16 floats)
  const int lane = tid & 63;
  const int w = tid >> 6;
  const int w0 = w & 1;             // wave row-half of tile
  const int w1 = w >> 1;            // wave col-half of tile
  const int quad = lane >> 4;
  const int l16 = lane & 15;

  f32x4_t acc[4][4];
#pragma unroll
  for (int i = 0; i < 4; i++)
#pragma unroll
    for (int j = 0; j < 4; j++)
#pragma unroll
      for (int r = 0; r < 4; r++) acc[i][j][r] = 0.f;

  const float* Arow = A + (size_t)(m0 + lr) * lda + lh * 16;
  const float* Wrow = W + (size_t)(n0 + lr) * K + lh * 16;
  _Float16* Adst = &As[lr * LSTR + lh * 16];
  _Float16* Bdst = &Bs[lr * LSTR + lh * 16];
  const _Float16* ab = &As[(w0 * 64 + l16) * LSTR + quad * 8];
  const _Float16* bb = &Bs[(w1 * 64 + l16) * LSTR + quad * 8];

  for (int k0 = 0; k0 < K; k0 += 32) {
    float4 a0 = *(const float4*)&Arow[k0];
    float4 a1 = *(const float4*)&Arow[k0 + 4];
    float4 a2 = *(const float4*)&Arow[k0 + 8];
    float4 a3 = *(const float4*)&Arow[k0 + 12];
    float4 w0v = *(const float4*)&Wrow[k0];
    float4 w1v = *(const float4*)&Wrow[k0 + 4];
    float4 w2v = *(const float4*)&Wrow[k0 + 8];
    float4 w3v = *(const float4*)&Wrow[k0 + 12];
    __syncthreads();
    {
      float xa[16] = {a0.x,a0.y,a0.z,a0.w, a1.x,a1.y,a1.z,a1.w,
                      a2.x,a2.y,a2.z,a2.w, a3.x,a3.y,a3.z,a3.w};
      f16x8 h0, h1, l0, l1;
#pragma unroll
      for (int i = 0; i < 8; i++) {
        _Float16 h = (_Float16)xa[i];
        h0[i] = h; l0[i] = (_Float16)(xa[i] - (float)h);
        _Float16 g = (_Float16)xa[8 + i];
        h1[i] = g; l1[i] = (_Float16)(xa[8 + i] - (float)g);
      }
      *(f16x8*)&Adst[0] = h0;
      *(f16x8*)&Adst[8] = h1;
      *(f16x8*)&Adst[32] = l0;
      *(f16x8*)&Adst[40] = l1;
      float xw[16] = {w0v.x,w0v.y,w0v.z,w0v.w, w1v.x,w1v.y,w1v.z,w1v.w,
                      w2v.x,w2v.y,w2v.z,w2v.w, w3v.x,w3v.y,w3v.z,w3v.w};
#pragma unroll
      for (int i = 0; i < 8; i++) {
        _Float16 h = (_Float16)xw[i];
        h0[i] = h; l0[i] = (_Float16)(xw[i] - (float)h);
        _Float16 g = (_Float16)xw[8 + i];
        h1[i] = g; l1[i] = (_Float16)(xw[8 + i] - (float)g);
      }
      *(f16x8*)&Bdst[0] = h0;
      *(f16x8*)&Bdst[8] = h1;
      *(f16x8*)&Bdst[32] = l0;
      *(f16x8*)&Bdst[40] = l1;
    }
    __syncthreads();

    f16x8 bh[4], bl[4];
#pragma unroll
    for (int ni = 0; ni < 4; ni++) {
      bh[ni] = *(const f16x8*)&bb[ni * 16 * LSTR];
      bl[ni] = *(const f16x8*)&bb[ni * 16 * LSTR + 32];
    }
#pragma unroll
    for (int mi = 0; mi < 4; mi++) {
      f16x8 ah = *(const f16x8*)&ab[mi * 16 * LSTR];
      f16x8 al = *(const f16x8*)&ab[mi * 16 * LSTR + 32];
#pragma unroll
      for (int ni = 0; ni < 4; ni++) {
        acc[mi][ni] = __builtin_amdgcn_mfma_f32_16x16x32_f16(ah, bh[ni], acc[mi][ni], 0, 0, 0);
        acc[mi][ni] = __builtin_amdgcn_mfma_f32_16x16x32_f16(ah, bl[ni], acc[mi][ni], 0, 0, 0);
        acc[mi][ni] = __builtin_amdgcn_mfma_f32_16x16x32_f16(al, bh[ni], acc[mi][ni], 0, 0, 0);
      }
    }
  }

  // Epilogue: C/D layout col=lane&15, row=quad*4+reg  [m89/m91 verified]
#pragma unroll
  for (int ni = 0; ni < 4; ni++) {
    const int n = n0 + w1 * 64 + ni * 16 + l16;
    const float bv = bias ? bias[n] : 0.f;
#pragma unroll
    for (int mi = 0; mi < 4; mi++) {
      const int mbase = m0 + w0 * 64 + mi * 16 + quad * 4;
#pragma unroll
      for (int r = 0; r < 4; r++) {
        float v = acc[mi][ni][r] + bv;
        if (act == 1) v = fmaxf(v, 0.f);
        else if (act == 2) v = fmaxf(v, 0.f) + log1pf(__expf(-fabsf(v)));
        C[(size_t)(mbase + r) * N + n] = v;
      }
    }
  }
}

// ---------------------------------------------------------------------------
// fp32 fallback GEMM (only xproj: N=64). 64x64 tile, 4x4/thr, K-step 16.
// ---------------------------------------------------------------------------
__global__ __launch_bounds__(256) void gemm_k(
    const float* __restrict__ A, int lda,
    const float* __restrict__ W,
    const float* __restrict__ bias,
    float* __restrict__ C,
    int N, int K, int act)
{
  __shared__ __align__(16) float As[16][64];
  __shared__ __align__(16) float Bs[16][64];
  const int tid = threadIdx.x;
  const int m0 = blockIdx.y * 64;
  const int n0 = blockIdx.x * 64;
  const int tr = tid >> 4;
  const int tc = tid & 15;
  const int lr = tid >> 2;
  const int lk = (tid & 3) << 2;

  float acc[4][4];
#pragma unroll
  for (int i = 0; i < 4; i++)
#pragma unroll
    for (int j = 0; j < 4; j++) acc[i][j] = 0.f;

  for (int k0 = 0; k0 < K; k0 += 16) {
    float4 av = *(const float4*)&A[(size_t)(m0 + lr) * lda + k0 + lk];
    float4 wv = *(const float4*)&W[(size_t)(n0 + lr) * K + k0 + lk];
    __syncthreads();
    As[lk + 0][lr] = av.x; As[lk + 1][lr] = av.y;
    As[lk + 2][lr] = av.z; As[lk + 3][lr] = av.w;
    Bs[lk + 0][lr] = wv.x; Bs[lk + 1][lr] = wv.y;
    Bs[lk + 2][lr] = wv.z; Bs[lk + 3][lr] = wv.w;
    __syncthreads();
#pragma unroll
    for (int kk = 0; kk < 16; ++kk) {
      float4 a = *(const float4*)&As[kk][tr * 4];
      float4 b = *(const float4*)&Bs[kk][tc * 4];
      float av4[4] = {a.x, a.y, a.z, a.w};
      float bv4[4] = {b.x, b.y, b.z, b.w};
#pragma unroll
      for (int i = 0; i < 4; i++)
#pragma unroll
        for (int j = 0; j < 4; j++) acc[i][j] += av4[i] * bv4[j];
    }
  }

#pragma unroll
  for (int i = 0; i < 4; i++) {
    const int m = m0 + tr * 4 + i;
    float4 o;
    float* po = (float*)&o;
#pragma unroll
    for (int j = 0; j < 4; j++) {
      float v = acc[i][j];
      const int n = n0 + tc * 4 + j;
      if (bias) v += bias[n];
      if (act == 1) v = fmaxf(v, 0.f);
      else if (act == 2) v = fmaxf(v, 0.f) + log1pf(__expf(-fabsf(v)));
      po[j] = v;
    }
    *(float4*)&C[(size_t)m * N + n0 + tc * 4] = o;
  }
}

// ---------------------------------------------------------------------------
// Attention phase 1: online-softmax partials over one key segment.
// ---------------------------------------------------------------------------
__global__ __launch_bounds__(256, 4) void attn_part_k(
    const float* __restrict__ qkv,
    float* __restrict__ Pacc, float* __restrict__ Pml)
{
  __shared__ __align__(16) float Ks[SEGK * 16];
  __shared__ __align__(16) float Vs[SEGK * 16];
  const int tid = threadIdx.x;
  const int qt  = blockIdx.x & 1;
  const int seg = blockIdx.x >> 1;
  const int bh = blockIdx.y;
  const int b = bh >> 3;
  const int h = bh & 7;
  const int t0 = qt * 512 + tid;
  const int t1 = t0 + 256;

  float q0[16], q1[16];
  {
    const float* qp0 = qkv + ((size_t)(b * TT + t0)) * 384 + h * 16;
    const float* qp1 = qkv + ((size_t)(b * TT + t1)) * 384 + h * 16;
#pragma unroll
    for (int p = 0; p < 4; p++) {
      float4 a = *(const float4*)&qp0[p * 4];
      q0[p*4+0] = a.x * 0.25f; q0[p*4+1] = a.y * 0.25f;
      q0[p*4+2] = a.z * 0.25f; q0[p*4+3] = a.w * 0.25f;
      float4 c = *(const float4*)&qp1[p * 4];
      q1[p*4+0] = c.x * 0.25f; q1[p*4+1] = c.y * 0.25f;
      q1[p*4+2] = c.z * 0.25f; q1[p*4+3] = c.w * 0.25f;
    }
  }

  const size_t baseK = ((size_t)(b * TT + seg * SEGK)) * 384 + 128 + h * 16;
  for (int idx = tid; idx < 512; idx += 256) {
    int row = idx >> 2, part = idx & 3;
    *(float4*)&Ks[row * 16 + part * 4] =
        *(const float4*)&qkv[baseK + (size_t)row * 384 + part * 4];
    *(float4*)&Vs[row * 16 + part * 4] =
        *(const float4*)&qkv[baseK + 128 + (size_t)row * 384 + part * 4];
  }
  __syncthreads();

  float m0 = -1e30f, l0 = 0.f, m1 = -1e30f, l1 = 0.f;
  float acc0[16], acc1[16];
#pragma unroll
  for (int d = 0; d < 16; d++) { acc0[d] = 0.f; acc1[d] = 0.f; }

  for (int j = 0; j < SEGK; j++) {
    float4 k0 = *(const float4*)&Ks[j * 16 + 0];
    float4 k1 = *(const float4*)&Ks[j * 16 + 4];
    float4 k2 = *(const float4*)&Ks[j * 16 + 8];
    float4 k3 = *(const float4*)&Ks[j * 16 + 12];
    float s0 = q0[0]*k0.x + q0[1]*k0.y + q0[2]*k0.z + q0[3]*k0.w
             + q0[4]*k1.x + q0[5]*k1.y + q0[6]*k1.z + q0[7]*k1.w
             + q0[8]*k2.x + q0[9]*k2.y + q0[10]*k2.z + q0[11]*k2.w
             + q0[12]*k3.x + q0[13]*k3.y + q0[14]*k3.z + q0[15]*k3.w;
    float s1 = q1[0]*k0.x + q1[1]*k0.y + q1[2]*k0.z + q1[3]*k0.w
             + q1[4]*k1.x + q1[5]*k1.y + q1[6]*k1.z + q1[7]*k1.w
             + q1[8]*k2.x + q1[9]*k2.y + q1[10]*k2.z + q1[11]*k2.w
             + q1[12]*k3.x + q1[13]*k3.y + q1[14]*k3.z + q1[15]*k3.w;
    if (s0 > m0) {
      float alpha = __expf(m0 - s0);
      l0 *= alpha;
#pragma unroll
      for (int d = 0; d < 16; d++) acc0[d] *= alpha;
      m0 = s0;
    }
    if (s1 > m1) {
      float alpha = __expf(m1 - s1);
      l1 *= alpha;
#pragma unroll
      for (int d = 0; d < 16; d++) acc1[d] *= alpha;
      m1 = s1;
    }
    float p0 = __expf(s0 - m0);
    float p1 = __expf(s1 - m1);
    l0 += p0; l1 += p1;
    float4 v0 = *(const float4*)&Vs[j * 16 + 0];
    float4 v1 = *(const float4*)&Vs[j * 16 + 4];
    float4 v2 = *(const float4*)&Vs[j * 16 + 8];
    float4 v3 = *(const float4*)&Vs[j * 16 + 12];
    acc0[0] += p0*v0.x; acc0[1] += p0*v0.y; acc0[2] += p0*v0.z; acc0[3] += p0*v0.w;
    acc0[4] += p0*v1.x; acc0[5] += p0*v1.y; acc0[6] += p0*v1.z; acc0[7] += p0*v1.w;
    acc0[8] += p0*v2.x; acc0[9] += p0*v2.y; acc0[10]+= p0*v2.z; acc0[11]+= p0*v2.w;
    acc0[12]+= p0*v3.x; acc0[13]+= p0*v3.y; acc0[14]+= p0*v3.z; acc0[15]+= p0*v3.w;
    acc1[0] += p1*v0.x; acc1[1] += p1*v0.y; acc1[2] += p1*v0.z; acc1[3] += p1*v0.w;
    acc1[4] += p1*v1.x; acc1[5] += p1*v1.y; acc1[6] += p1*v1.z; acc1[7] += p1*v1.w;
    acc1[8] += p1*v2.x; acc1[9] += p1*v2.y; acc1[10]+= p1*v2.z; acc1[11]+= p1*v2.w;
    acc1[12]+= p1*v3.x; acc1[13]+= p1*v3.y; acc1[14]+= p1*v3.z; acc1[15]+= p1*v3.w;
  }

  const size_t ps = (size_t)bh * NSEG + seg;
  float* pm = Pml + ps * 2048;
  pm[t0] = m0; pm[t1] = m1;
  pm[1024 + t0] = l0; pm[1024 + t1] = l1;
  float* pa = Pacc + ps * 16 * 1024;
#pragma unroll
  for (int d = 0; d < 16; d++) {
    pa[(size_t)d * 1024 + t0] = acc0[d];
    pa[(size_t)d * 1024 + t1] = acc1[d];
  }
}

// ---------------------------------------------------------------------------
// Attention phase 2: merge 8 segment partials -> o (M,128).
// ---------------------------------------------------------------------------
__global__ __launch_bounds__(256) void attn_comb_k(
    const float* __restrict__ Pacc, const float* __restrict__ Pml,
    float* __restrict__ o)
{
  const int idx = blockIdx.x * 256 + threadIdx.x;
  const int bh = idx >> 10;
  const int t = idx & 1023;
  const int b = bh >> 3;
  const int h = bh & 7;

  float ms[NSEG], ls[NSEG];
  float mstar = -1e30f;
#pragma unroll
  for (int s = 0; s < NSEG; s++) {
    const float* pm = Pml + ((size_t)bh * NSEG + s) * 2048;
    ms[s] = pm[t];
    ls[s] = pm[1024 + t];
    mstar = fmaxf(mstar, ms[s]);
  }
  float w[NSEG];
  float lstar = 0.f;
#pragma unroll
  for (int s = 0; s < NSEG; s++) {
    w[s] = __expf(ms[s] - mstar);
    lstar += w[s] * ls[s];
  }
  const float inv = 1.f / lstar;

  float out[16];
#pragma unroll
  for (int d = 0; d < 16; d++) out[d] = 0.f;
#pragma unroll
  for (int s = 0; s < NSEG; s++) {
    const float* pa = Pacc + ((size_t)bh * NSEG + s) * 16 * 1024;
#pragma unroll
    for (int d = 0; d < 16; d++) out[d] += w[s] * pa[(size_t)d * 1024 + t];
  }
  float* op = o + ((size_t)(b * TT + t)) * 128 + h * 16;
#pragma unroll
  for (int p = 0; p < 4; p++) {
    float4 ov;
    ov.x = out[p*4+0] * inv; ov.y = out[p*4+1] * inv;
    ov.z = out[p*4+2] * inv; ov.w = out[p*4+3] * inv;
    *(float4*)&op[p * 4] = ov;
  }
}

// ---------------------------------------------------------------------------
// out = LN(a + bvec) * w + bb
// ---------------------------------------------------------------------------
__global__ __launch_bounds__(256) void add_ln_k(
    const float* __restrict__ a, const float* __restrict__ bvec,
    const float* __restrict__ w, const float* __restrict__ bb,
    float* __restrict__ out)
{
  const int tid = threadIdx.x;
  const int wave = tid >> 6, lane = tid & 63;
  const size_t row = (size_t)blockIdx.x * 4 + wave;
  const float* pa = a + row * 128;
  const float* pb = bvec + row * 128;
  float v0 = pa[lane] + pb[lane];
  float v1 = pa[lane + 64] + pb[lane + 64];
  float s1 = v0 + v1, s2 = v0 * v0 + v1 * v1;
#pragma unroll
  for (int off = 32; off; off >>= 1) {
    s1 += __shfl_down(s1, off);
    s2 += __shfl_down(s2, off);
  }
  s1 = __shfl(s1, 0); s2 = __shfl(s2, 0);
  const float mean = s1 * (1.f / 128.f);
  const float var = s2 * (1.f / 128.f) - mean * mean;
  const float rs = rsqrtf(var + EPSV);
  out[row * 128 + lane]      = (v0 - mean) * rs * w[lane] + bb[lane];
  out[row * 128 + lane + 64] = (v1 - mean) * rs * w[lane + 64] + bb[lane + 64];
}

// ---------------------------------------------------------------------------
// Depthwise causal conv (DC=4) + SiLU
// ---------------------------------------------------------------------------
__global__ __launch_bounds__(256) void conv_silu_k(
    const float* __restrict__ xz, const float* __restrict__ cw,
    const float* __restrict__ cb, float* __restrict__ out)
{
  const int idx = blockIdx.x * 256 + threadIdx.x;
  const int di = idx & 1023;
  const int m = idx >> 10;
  const int t = m & (TT - 1);
  float acc = cb[di];
#pragma unroll
  for (int k = 0; k < 4; k++) {
    int tt = t + k - 3;
    if (tt >= 0) acc += xz[(size_t)(m + k - 3) * 2048 + di] * cw[di * 4 + k];
  }
  out[(size_t)m * 1024 + di] = acc / (1.f + __expf(-acc));
}

// ---------------------------------------------------------------------------
// Chunked selective scan, phase A: local scan, emit P=prod(dA), S=local h.
// ---------------------------------------------------------------------------
__global__ __launch_bounds__(64) void scan_partial_k(
    const float* __restrict__ dt,
    const float* __restrict__ dbc,
    const float* __restrict__ xi,
    const float* __restrict__ Alog,
    float* __restrict__ Pb, float* __restrict__ Sb)
{
  const int slice = blockIdx.x & 15;
  const int c = blockIdx.x >> 4;
  const int b = blockIdx.y;
  const int di = slice * 64 + threadIdx.x;

  float A[NSTATE];
#pragma unroll
  for (int n = 0; n < NSTATE; n++) A[n] = -__expf(Alog[di * NSTATE + n]);
  float h[NSTATE], P[NSTATE];
#pragma unroll
  for (int n = 0; n < NSTATE; n++) { h[n] = 0.f; P[n] = 1.f; }

  const size_t m0 = (size_t)b * TT + (size_t)c * CHUNK;
  for (int t = 0; t < CHUNK; t++) {
    const size_t m = m0 + t;
    const float dtv = dt[m * 1024 + di];
    const float xv  = xi[m * 1024 + di];
    const float dtx = dtv * xv;
#pragma unroll
    for (int n = 0; n < NSTATE; n++) {
      const float Bv = dbc[m * 64 + 32 + n];
      const float dA = __expf(dtv * A[n]);
      h[n] = h[n] * dA + dtx * Bv;
      P[n] *= dA;
    }
  }
  const size_t base = (((size_t)b * NCH + c) * NSTATE) * 1024 + di;
#pragma unroll
  for (int n = 0; n < NSTATE; n++) {
    Pb[base + (size_t)n * 1024] = P[n];
    Sb[base + (size_t)n * 1024] = h[n];
  }
}

// ---------------------------------------------------------------------------
// Phase B: sequential chunk fix-up per (b, di).
// ---------------------------------------------------------------------------
__global__ __launch_bounds__(256) void scan_fix_k(
    float* __restrict__ Pb, const float* __restrict__ Sb)
{
  const int idx = blockIdx.x * 256 + threadIdx.x;
  const int b = idx >> 10;
  const int di = idx & 1023;
  float h[NSTATE];
#pragma unroll
  for (int n = 0; n < NSTATE; n++) h[n] = 0.f;
  for (int c = 0; c < NCH; c++) {
    const size_t base = (((size_t)b * NCH + c) * NSTATE) * 1024 + di;
    float P[NSTATE], S[NSTATE];
#pragma unroll
    for (int n = 0; n < NSTATE; n++) {
      P[n] = Pb[base + (size_t)n * 1024];
      S[n] = Sb[base + (size_t)n * 1024];
    }
#pragma unroll
    for (int n = 0; n < NSTATE; n++) {
      Pb[base + (size_t)n * 1024] = h[n];
      h[n] = P[n] * h[n] + S[n];
    }
  }
}

// ---------------------------------------------------------------------------
// Phase C: re-run each chunk from h_in; y = dot(h,C) + D*x; *= silu(z).
// ---------------------------------------------------------------------------
__global__ __launch_bounds__(64) void scan_final_k(
    const float* __restrict__ dt,
    const float* __restrict__ dbc,
    const float* __restrict__ xi,
    const float* __restrict__ xz,
    const float* __restrict__ Alog,
    const float* __restrict__ Dp,
    const float* __restrict__ Hin,
    float* __restrict__ Y)
{
  const int slice = blockIdx.x & 15;
  const int c = blockIdx.x >> 4;
  const int b = blockIdx.y;
  const int di = slice * 64 + threadIdx.x;

  float A[NSTATE];
#pragma unroll
  for (int n = 0; n < NSTATE; n++) A[n] = -__expf(Alog[di * NSTATE + n]);
  const float Dv = Dp[di];
  float h[NSTATE];
  const size_t hbase = (((size_t)b * NCH + c) * NSTATE) * 1024 + di;
#pragma unroll
  for (int n = 0; n < NSTATE; n++) h[n] = Hin[hbase + (size_t)n * 1024];

  const size_t m0 = (size_t)b * TT + (size_t)c * CHUNK;
  for (int t = 0; t < CHUNK; t++) {
    const size_t m = m0 + t;
    const float dtv = dt[m * 1024 + di];
    const float xv  = xi[m * 1024 + di];
    const float zv  = xz[m * 2048 + 1024 + di];
    const float dtx = dtv * xv;
    float y = 0.f;
#pragma unroll
    for (int n = 0; n < NSTATE; n++) {
      const float Bv = dbc[m * 64 + 32 + n];
      const float Cv = dbc[m * 64 + 48 + n];
      const float dA = __expf(dtv * A[n]);
      h[n] = h[n] * dA + dtx * Bv;
      y += h[n] * Cv;
    }
    y += Dv * xv;
    y *= zv / (1.f + __expf(-zv));
    Y[m * 1024 + di] = y;
  }
}

// ---------------------------------------------------------------------------
extern "C" void kernel_launch(void* const* d_in, const int* in_sizes, int n_in,
                              void* d_out, int out_size, void* d_ws, size_t ws_size,
                              hipStream_t stream)
{
  const float* emb      = (const float*)d_in[0];
  const float* t_wqkv   = (const float*)d_in[1];
  const float* t_bqkv   = (const float*)d_in[2];
  const float* t_wo     = (const float*)d_in[3];
  const float* t_bo     = (const float*)d_in[4];
  const float* t_ln1w   = (const float*)d_in[5];
  const float* t_ln1b   = (const float*)d_in[6];
  const float* t_w1     = (const float*)d_in[7];
  const float* t_b1     = (const float*)d_in[8];
  const float* t_w2     = (const float*)d_in[9];
  const float* t_b2     = (const float*)d_in[10];
  const float* t_ln2w   = (const float*)d_in[11];
  const float* t_ln2b   = (const float*)d_in[12];
  const float* w_in     = (const float*)d_in[13];
  const float* b_in     = (const float*)d_in[14];
  const float* m_inproj = (const float*)d_in[15];
  const float* m_convw  = (const float*)d_in[16];
  const float* m_convb  = (const float*)d_in[17];
  const float* m_xproj  = (const float*)d_in[18];
  const float* m_dtw    = (const float*)d_in[19];
  const float* m_dtb    = (const float*)d_in[20];
  const float* m_Alog   = (const float*)d_in[21];
  const float* m_D      = (const float*)d_in[22];
  const float* m_outproj= (const float*)d_in[23];
  const float* w_out    = (const float*)d_in[24];
  const float* b_out    = (const float*)d_in[25];

  float* ws = (float*)d_ws;
  float* X0   = ws;                               // M*512
  float* X1   = X0 + (size_t)MM * 512;            // M*512
  float* Abuf = X1 + (size_t)MM * 512;            // M*2048 (qkv | ff1 | xz)
  float* Bf   = Abuf + (size_t)MM * 2048;         // M*1024 (xi_act)
  float* Cf   = Bf + (size_t)MM * 1024;           // M*1024 (wo-out | ff2 | dt | attn Pacc)
  float* Yb   = Cf + (size_t)MM * 1024;           // M*1024 (attn o | scan y)
  float* Db   = Yb + (size_t)MM * 1024;           // M*64   (dbc)
  float* Pml  = Db + (size_t)MM * 64;             // 64*8*2*1024 (attn m/l partials)

  dim3 blk(256);
  auto gemm = [&](const float* A, int lda, const float* W, const float* bias,
                  float* C, int N, int K, int act) {
    if ((N % 128) == 0 && (K % 32) == 0) {
      dim3 g(N / 128, MM / 128);
      hipLaunchKernelGGL(gemm_mfma_k, g, blk, 0, stream, A, lda, W, bias, C, N, K, act);
    } else {
      dim3 g(N / 64, MM / 64);
      hipLaunchKernelGGL(gemm_k, g, blk, 0, stream, A, lda, W, bias, C, N, K, act);
    }
  };

  const float* x = emb;
  for (int l = 0; l < NTT; l++) {
    gemm(x, 128, t_wqkv + (size_t)l * 384 * 128, t_bqkv + l * 384, Abuf, 384, 128, 0);
    hipLaunchKernelGGL(attn_part_k, dim3(2 * NSEG, HB * 8), blk, 0, stream,
                       Abuf, Cf, Pml);
    hipLaunchKernelGGL(attn_comb_k, dim3(HB * 8 * TT / 256), blk, 0, stream,
                       Cf, Pml, Yb);
    gemm(Yb, 128, t_wo + (size_t)l * 128 * 128, t_bo + l * 128, Cf, 128, 128, 0);
    hipLaunchKernelGGL(add_ln_k, dim3(MM / 4), blk, 0, stream,
                       x, Cf, t_ln1w + l * 128, t_ln1b + l * 128, X0);
    gemm(X0, 128, t_w1 + (size_t)l * 2048 * 128, t_b1 + l * 2048, Abuf, 2048, 128, 1);
    gemm(Abuf, 2048, t_w2 + (size_t)l * 128 * 2048, t_b2 + l * 128, Cf, 128, 2048, 0);
    hipLaunchKernelGGL(add_ln_k, dim3(MM / 4), blk, 0, stream,
                       X0, Cf, t_ln2w + l * 128, t_ln2b + l * 128, X0);
    x = X0;
  }

  gemm(X0, 128, w_in, b_in, X1, 512, 128, 0);

  float* xc = X1;
  float* xo = X0;
  for (int l = 0; l < NMM; l++) {
    gemm(xc, 512, m_inproj + (size_t)l * 2048 * 512, nullptr, Abuf, 2048, 512, 0);
    hipLaunchKernelGGL(conv_silu_k, dim3(MM * 1024 / 256), blk, 0, stream,
                       Abuf, m_convw + (size_t)l * 1024 * 4, m_convb + l * 1024, Bf);
    gemm(Bf, 1024, m_xproj + (size_t)l * 64 * 1024, nullptr, Db, 64, 1024, 0);
    gemm(Db, 64, m_dtw + (size_t)l * 1024 * 32, m_dtb + l * 1024, Cf, 1024, 32, 2);

    float* Pb = xo;
    float* Sb = xo + (size_t)HB * NCH * NSTATE * 1024;
    hipLaunchKernelGGL(scan_partial_k, dim3(16 * NCH, HB), dim3(64), 0, stream,
                       Cf, Db, Bf, m_Alog + (size_t)l * 1024 * 16, Pb, Sb);
    hipLaunchKernelGGL(scan_fix_k, dim3(MM / 1024 * 4), blk, 0, stream, Pb, Sb);
    hipLaunchKernelGGL(scan_final_k, dim3(16 * NCH, HB), dim3(64), 0, stream,
                       Cf, Db, Bf, Abuf,
                       m_Alog + (size_t)l * 1024 * 16, m_D + l * 1024, Pb, Yb);

    gemm(Yb, 1024, m_outproj + (size_t)l * 512 * 1024, nullptr, xo, 512, 1024, 0);
    float* tmp = xc; xc = xo; xo = tmp;
  }

  gemm(xc, 512, w_out, b_out, (float*)d_out, 128, 512, 0);
}

// Round 5
// 3872.072 us; speedup vs baseline: 2.8192x; 1.2442x over previous
//
#include <hip/hip_runtime.h>
#include <math.h>

#define HB 8
#define TT 1024
#define NSTATE 16
#define NTT 6
#define NMM 8
#define MM (HB*TT)   /* 8192 rows */
#define EPSV 1e-5f
#define CHUNK 64
#define NCH (TT/CHUNK)   /* 16 */
#define NSEG 8           /* attention key segments */
#define SEGK (TT/NSEG)   /* 128 keys per segment */
#define LSTR 72          /* LDS row stride in halves: [32 hi|32 lo|8 pad] */

typedef _Float16 f16x8 __attribute__((ext_vector_type(8)));
typedef float f32x4_t __attribute__((ext_vector_type(4)));

static __device__ inline void split8(const float4 a, const float4 b,
                                     f16x8& h, f16x8& l)
{
  float x[8] = {a.x, a.y, a.z, a.w, b.x, b.y, b.z, b.w};
#pragma unroll
  for (int i = 0; i < 8; i++) {
    _Float16 hi = (_Float16)x[i];
    h[i] = hi;
    l[i] = (_Float16)(x[i] - (float)hi);
  }
}

// ---------------------------------------------------------------------------
// fp16x3 split-precision MFMA GEMM, templated tile 128xTN, BK=32, optional
// split-K (gridDim.z = S): partials (no bias/act) go to P, else direct to C.
// ---------------------------------------------------------------------------
template<int TN>
__global__ __launch_bounds__(256) void gemm_mfma_t(
    const float* __restrict__ A, int lda,
    const float* __restrict__ W,
    const float* __restrict__ bias,
    float* __restrict__ C,
    float* __restrict__ P,
    int N, int K, int S, int act)
{
  __shared__ _Float16 As[128 * LSTR];
  __shared__ _Float16 Bs[TN * LSTR];
  const int tid = threadIdx.x;
  const int m0 = blockIdx.y * 128;
  const int n0 = blockIdx.x * TN;
  const int z = blockIdx.z;
  const int kchunk = K / S;
  const int kb = z * kchunk;
  const int ke = kb + kchunk;

  const int lr = tid >> 1;          // A staging row 0..127
  const int lh = tid & 1;           // A staging 16-float half
  const int lane = tid & 63;
  const int w = tid >> 6;
  const int quad = lane >> 4;
  const int l16 = lane & 15;

  const float* Arow = A + (size_t)(m0 + lr) * lda + lh * 16;
  _Float16* Adst = &As[lr * LSTR + lh * 16];

  constexpr int MI = (TN == 128) ? 4 : 2;
  const int w0 = (TN == 128) ? (w & 1) : w;       // wave row group
  const int w1 = (TN == 128) ? (w >> 1) : 0;      // wave col group
  const int rowbase = (TN == 128) ? w0 * 64 : w0 * 32;

  f32x4_t acc[MI][4];
#pragma unroll
  for (int i = 0; i < MI; i++)
#pragma unroll
    for (int j = 0; j < 4; j++)
#pragma unroll
      for (int r = 0; r < 4; r++) acc[i][j][r] = 0.f;

  const _Float16* ab = &As[(rowbase + l16) * LSTR + quad * 8];
  const _Float16* bb = &Bs[(w1 * 64 + l16) * LSTR + quad * 8];

  // B staging pointers
  const float* Wrow;
  _Float16* Bdst;
  if (TN == 128) {
    Wrow = W + (size_t)(n0 + lr) * K + lh * 16;
    Bdst = &Bs[lr * LSTR + lh * 16];
  } else {
    const int br = tid >> 2;        // 0..63
    const int bo = (tid & 3) * 8;   // 0,8,16,24
    Wrow = W + (size_t)(n0 + br) * K + bo;
    Bdst = &Bs[br * LSTR + bo];
  }

  for (int k0 = kb; k0 < ke; k0 += 32) {
    float4 a0 = *(const float4*)&Arow[k0];
    float4 a1 = *(const float4*)&Arow[k0 + 4];
    float4 a2 = *(const float4*)&Arow[k0 + 8];
    float4 a3 = *(const float4*)&Arow[k0 + 12];
    float4 b0 = *(const float4*)&Wrow[k0];
    float4 b1 = *(const float4*)&Wrow[k0 + 4];
    float4 b2, b3;
    if (TN == 128) {
      b2 = *(const float4*)&Wrow[k0 + 8];
      b3 = *(const float4*)&Wrow[k0 + 12];
    }
    __syncthreads();
    {
      f16x8 h, l;
      split8(a0, a1, h, l);
      *(f16x8*)&Adst[0] = h; *(f16x8*)&Adst[32] = l;
      split8(a2, a3, h, l);
      *(f16x8*)&Adst[8] = h; *(f16x8*)&Adst[40] = l;
      split8(b0, b1, h, l);
      *(f16x8*)&Bdst[0] = h; *(f16x8*)&Bdst[32] = l;
      if (TN == 128) {
        split8(b2, b3, h, l);
        *(f16x8*)&Bdst[8] = h; *(f16x8*)&Bdst[40] = l;
      }
    }
    __syncthreads();

    f16x8 bh[4], bl[4];
#pragma unroll
    for (int ni = 0; ni < 4; ni++) {
      bh[ni] = *(const f16x8*)&bb[ni * 16 * LSTR];
      bl[ni] = *(const f16x8*)&bb[ni * 16 * LSTR + 32];
    }
#pragma unroll
    for (int mi = 0; mi < MI; mi++) {
      f16x8 ah = *(const f16x8*)&ab[mi * 16 * LSTR];
      f16x8 al = *(const f16x8*)&ab[mi * 16 * LSTR + 32];
#pragma unroll
      for (int ni = 0; ni < 4; ni++) {
        acc[mi][ni] = __builtin_amdgcn_mfma_f32_16x16x32_f16(ah, bh[ni], acc[mi][ni], 0, 0, 0);
        acc[mi][ni] = __builtin_amdgcn_mfma_f32_16x16x32_f16(ah, bl[ni], acc[mi][ni], 0, 0, 0);
        acc[mi][ni] = __builtin_amdgcn_mfma_f32_16x16x32_f16(al, bh[ni], acc[mi][ni], 0, 0, 0);
      }
    }
  }

  float* dst = (S == 1) ? C : (P + (size_t)z * MM * N);
  // C/D layout: col=lane&15, row=quad*4+reg  [m89/m91 verified]
#pragma unroll
  for (int ni = 0; ni < 4; ni++) {
    const int n = n0 + w1 * 64 + ni * 16 + l16;
    const float bv = (S == 1 && bias) ? bias[n] : 0.f;
#pragma unroll
    for (int mi = 0; mi < MI; mi++) {
      const int mbase = m0 + rowbase + mi * 16 + quad * 4;
#pragma unroll
      for (int r = 0; r < 4; r++) {
        float v = acc[mi][ni][r] + bv;
        if (S == 1) {
          if (act == 1) v = fmaxf(v, 0.f);
          else if (act == 2) v = fmaxf(v, 0.f) + log1pf(__expf(-fabsf(v)));
        }
        dst[(size_t)(mbase + r) * N + n] = v;
      }
    }
  }
}

// ---------------------------------------------------------------------------
// Split-K reduce: C = act( sum_z P[z] + bias ). total4 = MM*N/4 elements.
// ---------------------------------------------------------------------------
__global__ __launch_bounds__(256) void reduce_k(
    const float* __restrict__ P, const float* __restrict__ bias,
    float* __restrict__ C, int nmask, int S, int act, int stride4)
{
  const int idx = blockIdx.x * 256 + threadIdx.x;
  float4 a = *(const float4*)&P[(size_t)idx * 4];
  for (int z = 1; z < S; z++) {
    float4 p = *(const float4*)&P[(size_t)(idx + z * (size_t)stride4) * 4];
    a.x += p.x; a.y += p.y; a.z += p.z; a.w += p.w;
  }
  if (bias) {
    float4 bv = *(const float4*)&bias[(idx * 4) & nmask];
    a.x += bv.x; a.y += bv.y; a.z += bv.z; a.w += bv.w;
  }
  if (act == 1) {
    a.x = fmaxf(a.x, 0.f); a.y = fmaxf(a.y, 0.f);
    a.z = fmaxf(a.z, 0.f); a.w = fmaxf(a.w, 0.f);
  } else if (act == 2) {
    a.x = fmaxf(a.x, 0.f) + log1pf(__expf(-fabsf(a.x)));
    a.y = fmaxf(a.y, 0.f) + log1pf(__expf(-fabsf(a.y)));
    a.z = fmaxf(a.z, 0.f) + log1pf(__expf(-fabsf(a.z)));
    a.w = fmaxf(a.w, 0.f) + log1pf(__expf(-fabsf(a.w)));
  }
  *(float4*)&C[(size_t)idx * 4] = a;
}

// ---------------------------------------------------------------------------
// Attention phase 1: online-softmax partials over one key segment.
// ---------------------------------------------------------------------------
__global__ __launch_bounds__(256, 4) void attn_part_k(
    const float* __restrict__ qkv,
    float* __restrict__ Pacc, float* __restrict__ Pml)
{
  __shared__ __align__(16) float Ks[SEGK * 16];
  __shared__ __align__(16) float Vs[SEGK * 16];
  const int tid = threadIdx.x;
  const int qt  = blockIdx.x & 1;
  const int seg = blockIdx.x >> 1;
  const int bh = blockIdx.y;
  const int b = bh >> 3;
  const int h = bh & 7;
  const int t0 = qt * 512 + tid;
  const int t1 = t0 + 256;

  float q0[16], q1[16];
  {
    const float* qp0 = qkv + ((size_t)(b * TT + t0)) * 384 + h * 16;
    const float* qp1 = qkv + ((size_t)(b * TT + t1)) * 384 + h * 16;
#pragma unroll
    for (int p = 0; p < 4; p++) {
      float4 a = *(const float4*)&qp0[p * 4];
      q0[p*4+0] = a.x * 0.25f; q0[p*4+1] = a.y * 0.25f;
      q0[p*4+2] = a.z * 0.25f; q0[p*4+3] = a.w * 0.25f;
      float4 c = *(const float4*)&qp1[p * 4];
      q1[p*4+0] = c.x * 0.25f; q1[p*4+1] = c.y * 0.25f;
      q1[p*4+2] = c.z * 0.25f; q1[p*4+3] = c.w * 0.25f;
    }
  }

  const size_t baseK = ((size_t)(b * TT + seg * SEGK)) * 384 + 128 + h * 16;
  for (int idx = tid; idx < 512; idx += 256) {
    int row = idx >> 2, part = idx & 3;
    *(float4*)&Ks[row * 16 + part * 4] =
        *(const float4*)&qkv[baseK + (size_t)row * 384 + part * 4];
    *(float4*)&Vs[row * 16 + part * 4] =
        *(const float4*)&qkv[baseK + 128 + (size_t)row * 384 + part * 4];
  }
  __syncthreads();

  float m0 = -1e30f, l0 = 0.f, m1 = -1e30f, l1 = 0.f;
  float acc0[16], acc1[16];
#pragma unroll
  for (int d = 0; d < 16; d++) { acc0[d] = 0.f; acc1[d] = 0.f; }

  for (int j = 0; j < SEGK; j++) {
    float4 k0 = *(const float4*)&Ks[j * 16 + 0];
    float4 k1 = *(const float4*)&Ks[j * 16 + 4];
    float4 k2 = *(const float4*)&Ks[j * 16 + 8];
    float4 k3 = *(const float4*)&Ks[j * 16 + 12];
    float s0 = q0[0]*k0.x + q0[1]*k0.y + q0[2]*k0.z + q0[3]*k0.w
             + q0[4]*k1.x + q0[5]*k1.y + q0[6]*k1.z + q0[7]*k1.w
             + q0[8]*k2.x + q0[9]*k2.y + q0[10]*k2.z + q0[11]*k2.w
             + q0[12]*k3.x + q0[13]*k3.y + q0[14]*k3.z + q0[15]*k3.w;
    float s1 = q1[0]*k0.x + q1[1]*k0.y + q1[2]*k0.z + q1[3]*k0.w
             + q1[4]*k1.x + q1[5]*k1.y + q1[6]*k1.z + q1[7]*k1.w
             + q1[8]*k2.x + q1[9]*k2.y + q1[10]*k2.z + q1[11]*k2.w
             + q1[12]*k3.x + q1[13]*k3.y + q1[14]*k3.z + q1[15]*k3.w;
    if (s0 > m0) {
      float alpha = __expf(m0 - s0);
      l0 *= alpha;
#pragma unroll
      for (int d = 0; d < 16; d++) acc0[d] *= alpha;
      m0 = s0;
    }
    if (s1 > m1) {
      float alpha = __expf(m1 - s1);
      l1 *= alpha;
#pragma unroll
      for (int d = 0; d < 16; d++) acc1[d] *= alpha;
      m1 = s1;
    }
    float p0 = __expf(s0 - m0);
    float p1 = __expf(s1 - m1);
    l0 += p0; l1 += p1;
    float4 v0 = *(const float4*)&Vs[j * 16 + 0];
    float4 v1 = *(const float4*)&Vs[j * 16 + 4];
    float4 v2 = *(const float4*)&Vs[j * 16 + 8];
    float4 v3 = *(const float4*)&Vs[j * 16 + 12];
    acc0[0] += p0*v0.x; acc0[1] += p0*v0.y; acc0[2] += p0*v0.z; acc0[3] += p0*v0.w;
    acc0[4] += p0*v1.x; acc0[5] += p0*v1.y; acc0[6] += p0*v1.z; acc0[7] += p0*v1.w;
    acc0[8] += p0*v2.x; acc0[9] += p0*v2.y; acc0[10]+= p0*v2.z; acc0[11]+= p0*v2.w;
    acc0[12]+= p0*v3.x; acc0[13]+= p0*v3.y; acc0[14]+= p0*v3.z; acc0[15]+= p0*v3.w;
    acc1[0] += p1*v0.x; acc1[1] += p1*v0.y; acc1[2] += p1*v0.z; acc1[3] += p1*v0.w;
    acc1[4] += p1*v1.x; acc1[5] += p1*v1.y; acc1[6] += p1*v1.z; acc1[7] += p1*v1.w;
    acc1[8] += p1*v2.x; acc1[9] += p1*v2.y; acc1[10]+= p1*v2.z; acc1[11]+= p1*v2.w;
    acc1[12]+= p1*v3.x; acc1[13]+= p1*v3.y; acc1[14]+= p1*v3.z; acc1[15]+= p1*v3.w;
  }

  const size_t ps = (size_t)bh * NSEG + seg;
  float* pm = Pml + ps * 2048;
  pm[t0] = m0; pm[t1] = m1;
  pm[1024 + t0] = l0; pm[1024 + t1] = l1;
  float* pa = Pacc + ps * 16 * 1024;
#pragma unroll
  for (int d = 0; d < 16; d++) {
    pa[(size_t)d * 1024 + t0] = acc0[d];
    pa[(size_t)d * 1024 + t1] = acc1[d];
  }
}

// ---------------------------------------------------------------------------
// Attention phase 2: merge 8 segment partials -> o (M,128).
// ---------------------------------------------------------------------------
__global__ __launch_bounds__(256) void attn_comb_k(
    const float* __restrict__ Pacc, const float* __restrict__ Pml,
    float* __restrict__ o)
{
  const int idx = blockIdx.x * 256 + threadIdx.x;
  const int bh = idx >> 10;
  const int t = idx & 1023;
  const int b = bh >> 3;
  const int h = bh & 7;

  float ms[NSEG], ls[NSEG];
  float mstar = -1e30f;
#pragma unroll
  for (int s = 0; s < NSEG; s++) {
    const float* pm = Pml + ((size_t)bh * NSEG + s) * 2048;
    ms[s] = pm[t];
    ls[s] = pm[1024 + t];
    mstar = fmaxf(mstar, ms[s]);
  }
  float w[NSEG];
  float lstar = 0.f;
#pragma unroll
  for (int s = 0; s < NSEG; s++) {
    w[s] = __expf(ms[s] - mstar);
    lstar += w[s] * ls[s];
  }
  const float inv = 1.f / lstar;

  float out[16];
#pragma unroll
  for (int d = 0; d < 16; d++) out[d] = 0.f;
#pragma unroll
  for (int s = 0; s < NSEG; s++) {
    const float* pa = Pacc + ((size_t)bh * NSEG + s) * 16 * 1024;
#pragma unroll
    for (int d = 0; d < 16; d++) out[d] += w[s] * pa[(size_t)d * 1024 + t];
  }
  float* op = o + ((size_t)(b * TT + t)) * 128 + h * 16;
#pragma unroll
  for (int p = 0; p < 4; p++) {
    float4 ov;
    ov.x = out[p*4+0] * inv; ov.y = out[p*4+1] * inv;
    ov.z = out[p*4+2] * inv; ov.w = out[p*4+3] * inv;
    *(float4*)&op[p * 4] = ov;
  }
}

// ---------------------------------------------------------------------------
// out = LN(a + bvec) * w + bb
// ---------------------------------------------------------------------------
__global__ __launch_bounds__(256) void add_ln_k(
    const float* __restrict__ a, const float* __restrict__ bvec,
    const float* __restrict__ w, const float* __restrict__ bb,
    float* __restrict__ out)
{
  const int tid = threadIdx.x;
  const int wave = tid >> 6, lane = tid & 63;
  const size_t row = (size_t)blockIdx.x * 4 + wave;
  const float* pa = a + row * 128;
  const float* pb = bvec + row * 128;
  float v0 = pa[lane] + pb[lane];
  float v1 = pa[lane + 64] + pb[lane + 64];
  float s1 = v0 + v1, s2 = v0 * v0 + v1 * v1;
#pragma unroll
  for (int off = 32; off; off >>= 1) {
    s1 += __shfl_down(s1, off);
    s2 += __shfl_down(s2, off);
  }
  s1 = __shfl(s1, 0); s2 = __shfl(s2, 0);
  const float mean = s1 * (1.f / 128.f);
  const float var = s2 * (1.f / 128.f) - mean * mean;
  const float rs = rsqrtf(var + EPSV);
  out[row * 128 + lane]      = (v0 - mean) * rs * w[lane] + bb[lane];
  out[row * 128 + lane + 64] = (v1 - mean) * rs * w[lane + 64] + bb[lane + 64];
}

// ---------------------------------------------------------------------------
// Depthwise causal conv (DC=4) + SiLU
// ---------------------------------------------------------------------------
__global__ __launch_bounds__(256) void conv_silu_k(
    const float* __restrict__ xz, const float* __restrict__ cw,
    const float* __restrict__ cb, float* __restrict__ out)
{
  const int idx = blockIdx.x * 256 + threadIdx.x;
  const int di = idx & 1023;
  const int m = idx >> 10;
  const int t = m & (TT - 1);
  float acc = cb[di];
#pragma unroll
  for (int k = 0; k < 4; k++) {
    int tt = t + k - 3;
    if (tt >= 0) acc += xz[(size_t)(m + k - 3) * 2048 + di] * cw[di * 4 + k];
  }
  out[(size_t)m * 1024 + di] = acc / (1.f + __expf(-acc));
}

// ---------------------------------------------------------------------------
// Chunked selective scan, phase A: local scan, emit P=prod(dA), S=local h.
// ---------------------------------------------------------------------------
__global__ __launch_bounds__(64) void scan_partial_k(
    const float* __restrict__ dt,
    const float* __restrict__ dbc,
    const float* __restrict__ xi,
    const float* __restrict__ Alog,
    float* __restrict__ Pb, float* __restrict__ Sb)
{
  const int slice = blockIdx.x & 15;
  const int c = blockIdx.x >> 4;
  const int b = blockIdx.y;
  const int di = slice * 64 + threadIdx.x;

  float A[NSTATE];
#pragma unroll
  for (int n = 0; n < NSTATE; n++) A[n] = -__expf(Alog[di * NSTATE + n]);
  float h[NSTATE], P[NSTATE];
#pragma unroll
  for (int n = 0; n < NSTATE; n++) { h[n] = 0.f; P[n] = 1.f; }

  const size_t m0 = (size_t)b * TT + (size_t)c * CHUNK;
  for (int t = 0; t < CHUNK; t++) {
    const size_t m = m0 + t;
    const float dtv = dt[m * 1024 + di];
    const float xv  = xi[m * 1024 + di];
    const float dtx = dtv * xv;
#pragma unroll
    for (int n = 0; n < NSTATE; n++) {
      const float Bv = dbc[m * 64 + 32 + n];
      const float dA = __expf(dtv * A[n]);
      h[n] = h[n] * dA + dtx * Bv;
      P[n] *= dA;
    }
  }
  const size_t base = (((size_t)b * NCH + c) * NSTATE) * 1024 + di;
#pragma unroll
  for (int n = 0; n < NSTATE; n++) {
    Pb[base + (size_t)n * 1024] = P[n];
    Sb[base + (size_t)n * 1024] = h[n];
  }
}

// ---------------------------------------------------------------------------
// Phase B: sequential chunk fix-up per (b, di).
// ---------------------------------------------------------------------------
__global__ __launch_bounds__(256) void scan_fix_k(
    float* __restrict__ Pb, const float* __restrict__ Sb)
{
  const int idx = blockIdx.x * 256 + threadIdx.x;
  const int b = idx >> 10;
  const int di = idx & 1023;
  float h[NSTATE];
#pragma unroll
  for (int n = 0; n < NSTATE; n++) h[n] = 0.f;
  for (int c = 0; c < NCH; c++) {
    const size_t base = (((size_t)b * NCH + c) * NSTATE) * 1024 + di;
    float P[NSTATE], S[NSTATE];
#pragma unroll
    for (int n = 0; n < NSTATE; n++) {
      P[n] = Pb[base + (size_t)n * 1024];
      S[n] = Sb[base + (size_t)n * 1024];
    }
#pragma unroll
    for (int n = 0; n < NSTATE; n++) {
      Pb[base + (size_t)n * 1024] = h[n];
      h[n] = P[n] * h[n] + S[n];
    }
  }
}

// ---------------------------------------------------------------------------
// Phase C: re-run each chunk from h_in; y = dot(h,C) + D*x; *= silu(z).
// ---------------------------------------------------------------------------
__global__ __launch_bounds__(64) void scan_final_k(
    const float* __restrict__ dt,
    const float* __restrict__ dbc,
    const float* __restrict__ xi,
    const float* __restrict__ xz,
    const float* __restrict__ Alog,
    const float* __restrict__ Dp,
    const float* __restrict__ Hin,
    float* __restrict__ Y)
{
  const int slice = blockIdx.x & 15;
  const int c = blockIdx.x >> 4;
  const int b = blockIdx.y;
  const int di = slice * 64 + threadIdx.x;

  float A[NSTATE];
#pragma unroll
  for (int n = 0; n < NSTATE; n++) A[n] = -__expf(Alog[di * NSTATE + n]);
  const float Dv = Dp[di];
  float h[NSTATE];
  const size_t hbase = (((size_t)b * NCH + c) * NSTATE) * 1024 + di;
#pragma unroll
  for (int n = 0; n < NSTATE; n++) h[n] = Hin[hbase + (size_t)n * 1024];

  const size_t m0 = (size_t)b * TT + (size_t)c * CHUNK;
  for (int t = 0; t < CHUNK; t++) {
    const size_t m = m0 + t;
    const float dtv = dt[m * 1024 + di];
    const float xv  = xi[m * 1024 + di];
    const float zv  = xz[m * 2048 + 1024 + di];
    const float dtx = dtv * xv;
    float y = 0.f;
#pragma unroll
    for (int n = 0; n < NSTATE; n++) {
      const float Bv = dbc[m * 64 + 32 + n];
      const float Cv = dbc[m * 64 + 48 + n];
      const float dA = __expf(dtv * A[n]);
      h[n] = h[n] * dA + dtx * Bv;
      y += h[n] * Cv;
    }
    y += Dv * xv;
    y *= zv / (1.f + __expf(-zv));
    Y[m * 1024 + di] = y;
  }
}

// ---------------------------------------------------------------------------
extern "C" void kernel_launch(void* const* d_in, const int* in_sizes, int n_in,
                              void* d_out, int out_size, void* d_ws, size_t ws_size,
                              hipStream_t stream)
{
  const float* emb      = (const float*)d_in[0];
  const float* t_wqkv   = (const float*)d_in[1];
  const float* t_bqkv   = (const float*)d_in[2];
  const float* t_wo     = (const float*)d_in[3];
  const float* t_bo     = (const float*)d_in[4];
  const float* t_ln1w   = (const float*)d_in[5];
  const float* t_ln1b   = (const float*)d_in[6];
  const float* t_w1     = (const float*)d_in[7];
  const float* t_b1     = (const float*)d_in[8];
  const float* t_w2     = (const float*)d_in[9];
  const float* t_b2     = (const float*)d_in[10];
  const float* t_ln2w   = (const float*)d_in[11];
  const float* t_ln2b   = (const float*)d_in[12];
  const float* w_in     = (const float*)d_in[13];
  const float* b_in     = (const float*)d_in[14];
  const float* m_inproj = (const float*)d_in[15];
  const float* m_convw  = (const float*)d_in[16];
  const float* m_convb  = (const float*)d_in[17];
  const float* m_xproj  = (const float*)d_in[18];
  const float* m_dtw    = (const float*)d_in[19];
  const float* m_dtb    = (const float*)d_in[20];
  const float* m_Alog   = (const float*)d_in[21];
  const float* m_D      = (const float*)d_in[22];
  const float* m_outproj= (const float*)d_in[23];
  const float* w_out    = (const float*)d_in[24];
  const float* b_out    = (const float*)d_in[25];

  float* ws = (float*)d_ws;
  float* X0   = ws;                               // M*512
  float* X1   = X0 + (size_t)MM * 512;            // M*512
  float* Abuf = X1 + (size_t)MM * 512;            // M*2048 (qkv | ff1 | xz)
  float* Bf   = Abuf + (size_t)MM * 2048;         // M*1024 (xi_act)
  float* Cf   = Bf + (size_t)MM * 1024;           // M*1024 (wo-out | ff2 | dt | attn Pacc)
  float* Yb   = Cf + (size_t)MM * 1024;           // M*1024 (attn o | scan y)
  float* Db   = Yb + (size_t)MM * 1024;           // M*64   (dbc)
  float* Pml  = Db + (size_t)MM * 64;             // 64*8*2*1024 (attn m/l)

  dim3 blk(256);
  // generic launcher: tn64 picks the 128x64 tile; S>1 does split-K via P
  auto gemm = [&](const float* A, int lda, const float* W, const float* bias,
                  float* C, int N, int K, int act, int S, float* P, bool tn64) {
    dim3 g(N / (tn64 ? 64 : 128), MM / 128, S);
    if (tn64)
      hipLaunchKernelGGL(gemm_mfma_t<64>, g, blk, 0, stream,
                         A, lda, W, S == 1 ? bias : nullptr, C, P, N, K, S, act);
    else
      hipLaunchKernelGGL(gemm_mfma_t<128>, g, blk, 0, stream,
                         A, lda, W, S == 1 ? bias : nullptr, C, P, N, K, S, act);
    if (S > 1) {
      int stride4 = (MM * N) / 4;
      hipLaunchKernelGGL(reduce_k, dim3(stride4 / 256), blk, 0, stream,
                         P, bias, C, N - 1, S, act, stride4);
    }
  };

  const float* x = emb;
  for (int l = 0; l < NTT; l++) {
    // qkv: N=384 K=128
    gemm(x, 128, t_wqkv + (size_t)l * 384 * 128, t_bqkv + l * 384,
         Abuf, 384, 128, 0, 1, nullptr, false);
    hipLaunchKernelGGL(attn_part_k, dim3(2 * NSEG, HB * 8), blk, 0, stream,
                       Abuf, Cf, Pml);
    hipLaunchKernelGGL(attn_comb_k, dim3(HB * 8 * TT / 256), blk, 0, stream,
                       Cf, Pml, Yb);
    // wo: N=128 K=128 -> TN64, S=2, partials in X1 (dead during transformers)
    gemm(Yb, 128, t_wo + (size_t)l * 128 * 128, t_bo + l * 128,
         Cf, 128, 128, 0, 2, X1, true);
    hipLaunchKernelGGL(add_ln_k, dim3(MM / 4), blk, 0, stream,
                       x, Cf, t_ln1w + l * 128, t_ln1b + l * 128, X0);
    // w1: N=2048 K=128
    gemm(X0, 128, t_w1 + (size_t)l * 2048 * 128, t_b1 + l * 2048,
         Abuf, 2048, 128, 1, 1, nullptr, false);
    // w2: N=128 K=2048 -> S=8, partials in Yb (dead after wo)
    gemm(Abuf, 2048, t_w2 + (size_t)l * 128 * 2048, t_b2 + l * 128,
         Cf, 128, 2048, 0, 8, Yb, false);
    hipLaunchKernelGGL(add_ln_k, dim3(MM / 4), blk, 0, stream,
                       X0, Cf, t_ln2w + l * 128, t_ln2b + l * 128, X0);
    x = X0;
  }

  // w_in: N=512 K=128
  gemm(X0, 128, w_in, b_in, X1, 512, 128, 0, 1, nullptr, false);

  float* xc = X1;
  float* xo = X0;
  for (int l = 0; l < NMM; l++) {
    // inproj: N=2048 K=512
    gemm(xc, 512, m_inproj + (size_t)l * 2048 * 512, nullptr,
         Abuf, 2048, 512, 0, 1, nullptr, false);
    hipLaunchKernelGGL(conv_silu_k, dim3(MM * 1024 / 256), blk, 0, stream,
                       Abuf, m_convw + (size_t)l * 1024 * 4, m_convb + l * 1024, Bf);
    // xproj: N=64 K=1024 -> TN64, S=4, partials in xo (before scan uses it)
    gemm(Bf, 1024, m_xproj + (size_t)l * 64 * 1024, nullptr,
         Db, 64, 1024, 0, 4, xo, true);
    // dtw: N=1024 K=32, softplus
    gemm(Db, 64, m_dtw + (size_t)l * 1024 * 32, m_dtb + l * 1024,
         Cf, 1024, 32, 2, 1, nullptr, false);

    float* Pb = xo;
    float* Sb = xo + (size_t)HB * NCH * NSTATE * 1024;
    hipLaunchKernelGGL(scan_partial_k, dim3(16 * NCH, HB), dim3(64), 0, stream,
                       Cf, Db, Bf, m_Alog + (size_t)l * 1024 * 16, Pb, Sb);
    hipLaunchKernelGGL(scan_fix_k, dim3(MM / 1024 * 4), blk, 0, stream, Pb, Sb);
    hipLaunchKernelGGL(scan_final_k, dim3(16 * NCH, HB), dim3(64), 0, stream,
                       Cf, Db, Bf, Abuf,
                       m_Alog + (size_t)l * 1024 * 16, m_D + l * 1024, Pb, Yb);

    // outproj: N=512 K=1024 -> S=2, partials in Abuf (xz dead after scan_final)
    gemm(Yb, 1024, m_outproj + (size_t)l * 512 * 1024, nullptr,
         xo, 512, 1024, 0, 2, Abuf, false);
    float* tmp = xc; xc = xo; xo = tmp;
  }

  // w_out: N=128 K=512 -> S=4, partials in Yb (dead)
  gemm(xc, 512, w_out, b_out, (float*)d_out, 128, 512, 0, 4, Yb, false);
}

// Round 6
// 3640.794 us; speedup vs baseline: 2.9982x; 1.0635x over previous
//
#include <hip/hip_runtime.h>
#include <math.h>

#define HB 8
#define TT 1024
#define NSTATE 16
#define NTT 6
#define NMM 8
#define MM (HB*TT)   /* 8192 rows */
#define EPSV 1e-5f
#define CHUNK 64
#define NCH (TT/CHUNK)   /* 16 */
#define LSTR 72          /* GEMM LDS row stride in halves: [32 hi|32 lo|8 pad] */
#define AKS 128          /* attention keys staged per block iter */
#define VSTR 132         /* V-transpose LDS stride (halves) */

typedef _Float16 f16x8 __attribute__((ext_vector_type(8)));
typedef _Float16 f16x4 __attribute__((ext_vector_type(4)));
typedef float f32x4_t __attribute__((ext_vector_type(4)));

static __device__ inline void split8(const float4 a, const float4 b,
                                     f16x8& h, f16x8& l)
{
  float x[8] = {a.x, a.y, a.z, a.w, b.x, b.y, b.z, b.w};
#pragma unroll
  for (int i = 0; i < 8; i++) {
    _Float16 hi = (_Float16)x[i];
    h[i] = hi;
    l[i] = (_Float16)(x[i] - (float)hi);
  }
}

// ---------------------------------------------------------------------------
// fp16x3 split-precision MFMA GEMM, templated tile 128xTN, BK=32, optional
// split-K (gridDim.z = S): partials (no bias/act) go to P, else direct to C.
// ---------------------------------------------------------------------------
template<int TN>
__global__ __launch_bounds__(256) void gemm_mfma_t(
    const float* __restrict__ A, int lda,
    const float* __restrict__ W,
    const float* __restrict__ bias,
    float* __restrict__ C,
    float* __restrict__ P,
    int N, int K, int S, int act)
{
  __shared__ _Float16 As[128 * LSTR];
  __shared__ _Float16 Bs[TN * LSTR];
  const int tid = threadIdx.x;
  const int m0 = blockIdx.y * 128;
  const int n0 = blockIdx.x * TN;
  const int z = blockIdx.z;
  const int kchunk = K / S;
  const int kb = z * kchunk;
  const int ke = kb + kchunk;

  const int lr = tid >> 1;
  const int lh = tid & 1;
  const int lane = tid & 63;
  const int w = tid >> 6;
  const int quad = lane >> 4;
  const int l16 = lane & 15;

  const float* Arow = A + (size_t)(m0 + lr) * lda + lh * 16;
  _Float16* Adst = &As[lr * LSTR + lh * 16];

  constexpr int MI = (TN == 128) ? 4 : 2;
  const int w0 = (TN == 128) ? (w & 1) : w;
  const int w1 = (TN == 128) ? (w >> 1) : 0;
  const int rowbase = (TN == 128) ? w0 * 64 : w0 * 32;

  f32x4_t acc[MI][4];
#pragma unroll
  for (int i = 0; i < MI; i++)
#pragma unroll
    for (int j = 0; j < 4; j++)
#pragma unroll
      for (int r = 0; r < 4; r++) acc[i][j][r] = 0.f;

  const _Float16* ab = &As[(rowbase + l16) * LSTR + quad * 8];
  const _Float16* bb = &Bs[(w1 * 64 + l16) * LSTR + quad * 8];

  const float* Wrow;
  _Float16* Bdst;
  if (TN == 128) {
    Wrow = W + (size_t)(n0 + lr) * K + lh * 16;
    Bdst = &Bs[lr * LSTR + lh * 16];
  } else {
    const int br = tid >> 2;
    const int bo = (tid & 3) * 8;
    Wrow = W + (size_t)(n0 + br) * K + bo;
    Bdst = &Bs[br * LSTR + bo];
  }

  for (int k0 = kb; k0 < ke; k0 += 32) {
    float4 a0 = *(const float4*)&Arow[k0];
    float4 a1 = *(const float4*)&Arow[k0 + 4];
    float4 a2 = *(const float4*)&Arow[k0 + 8];
    float4 a3 = *(const float4*)&Arow[k0 + 12];
    float4 b0 = *(const float4*)&Wrow[k0];
    float4 b1 = *(const float4*)&Wrow[k0 + 4];
    float4 b2, b3;
    if (TN == 128) {
      b2 = *(const float4*)&Wrow[k0 + 8];
      b3 = *(const float4*)&Wrow[k0 + 12];
    }
    __syncthreads();
    {
      f16x8 h, l;
      split8(a0, a1, h, l);
      *(f16x8*)&Adst[0] = h; *(f16x8*)&Adst[32] = l;
      split8(a2, a3, h, l);
      *(f16x8*)&Adst[8] = h; *(f16x8*)&Adst[40] = l;
      split8(b0, b1, h, l);
      *(f16x8*)&Bdst[0] = h; *(f16x8*)&Bdst[32] = l;
      if (TN == 128) {
        split8(b2, b3, h, l);
        *(f16x8*)&Bdst[8] = h; *(f16x8*)&Bdst[40] = l;
      }
    }
    __syncthreads();

    f16x8 bh[4], bl[4];
#pragma unroll
    for (int ni = 0; ni < 4; ni++) {
      bh[ni] = *(const f16x8*)&bb[ni * 16 * LSTR];
      bl[ni] = *(const f16x8*)&bb[ni * 16 * LSTR + 32];
    }
#pragma unroll
    for (int mi = 0; mi < MI; mi++) {
      f16x8 ah = *(const f16x8*)&ab[mi * 16 * LSTR];
      f16x8 al = *(const f16x8*)&ab[mi * 16 * LSTR + 32];
#pragma unroll
      for (int ni = 0; ni < 4; ni++) {
        acc[mi][ni] = __builtin_amdgcn_mfma_f32_16x16x32_f16(ah, bh[ni], acc[mi][ni], 0, 0, 0);
        acc[mi][ni] = __builtin_amdgcn_mfma_f32_16x16x32_f16(ah, bl[ni], acc[mi][ni], 0, 0, 0);
        acc[mi][ni] = __builtin_amdgcn_mfma_f32_16x16x32_f16(al, bh[ni], acc[mi][ni], 0, 0, 0);
      }
    }
  }

  float* dst = (S == 1) ? C : (P + (size_t)z * MM * N);
#pragma unroll
  for (int ni = 0; ni < 4; ni++) {
    const int n = n0 + w1 * 64 + ni * 16 + l16;
    const float bv = (S == 1 && bias) ? bias[n] : 0.f;
#pragma unroll
    for (int mi = 0; mi < MI; mi++) {
      const int mbase = m0 + rowbase + mi * 16 + quad * 4;
#pragma unroll
      for (int r = 0; r < 4; r++) {
        float v = acc[mi][ni][r] + bv;
        if (S == 1) {
          if (act == 1) v = fmaxf(v, 0.f);
          else if (act == 2) v = fmaxf(v, 0.f) + log1pf(__expf(-fabsf(v)));
        }
        dst[(size_t)(mbase + r) * N + n] = v;
      }
    }
  }
}

// ---------------------------------------------------------------------------
// Split-K reduce: C = act( sum_z P[z] + bias ).
// ---------------------------------------------------------------------------
__global__ __launch_bounds__(256) void reduce_k(
    const float* __restrict__ P, const float* __restrict__ bias,
    float* __restrict__ C, int nmask, int S, int act, int stride4)
{
  const int idx = blockIdx.x * 256 + threadIdx.x;
  float4 a = *(const float4*)&P[(size_t)idx * 4];
  for (int z = 1; z < S; z++) {
    float4 p = *(const float4*)&P[(size_t)(idx + z * (size_t)stride4) * 4];
    a.x += p.x; a.y += p.y; a.z += p.z; a.w += p.w;
  }
  if (bias) {
    float4 bv = *(const float4*)&bias[(idx * 4) & nmask];
    a.x += bv.x; a.y += bv.y; a.z += bv.z; a.w += bv.w;
  }
  if (act == 1) {
    a.x = fmaxf(a.x, 0.f); a.y = fmaxf(a.y, 0.f);
    a.z = fmaxf(a.z, 0.f); a.w = fmaxf(a.w, 0.f);
  } else if (act == 2) {
    a.x = fmaxf(a.x, 0.f) + log1pf(__expf(-fabsf(a.x)));
    a.y = fmaxf(a.y, 0.f) + log1pf(__expf(-fabsf(a.y)));
    a.z = fmaxf(a.z, 0.f) + log1pf(__expf(-fabsf(a.z)));
    a.w = fmaxf(a.w, 0.f) + log1pf(__expf(-fabsf(a.w)));
  }
  *(float4*)&C[(size_t)idx * 4] = a;
}

// ---------------------------------------------------------------------------
// MFMA flash attention (no-max softmax: scores bounded |s|<~3 by construction).
// qkv (M,384) = [q|k|v], 8 heads x 16 dim, scale 0.25 folded into q.
// Block: 256 thr = 4 waves; 128 queries/block (wave: 2 q-tiles of 16).
// Split-precision trick: K-dim packing [hi|lo] with duplicated B halves gives
// exact fp32-grade products in 2 MFMA.
// grid (TT/128, B*H).
// ---------------------------------------------------------------------------
__global__ __launch_bounds__(256) void attn_mfma_k(
    const float* __restrict__ qkv, float* __restrict__ o)
{
  __shared__ _Float16 Khi[AKS * 16], Klo[AKS * 16];
  __shared__ _Float16 Vthi[16 * VSTR], Vtlo[16 * VSTR];
  __shared__ float Pscr[4][16 * 18];

  const int tid = threadIdx.x;
  const int lane = tid & 63;
  const int wv = tid >> 6;
  const int quad = lane >> 4;
  const int l16 = lane & 15;
  const int qh = quad & 1;          // which 8-dim half this quad covers
  const int bh = blockIdx.y;
  const int b = bh >> 3;
  const int h = bh & 7;
  const int qb0 = blockIdx.x * 128;

  // Q A-frags: A[m=l16][k=quad*8+j]; k 0..15 = q_hi dims, 16..31 = q_lo dims
  f16x8 qa[2];
#pragma unroll
  for (int u = 0; u < 2; u++) {
    const int qrow = qb0 + wv * 32 + u * 16 + l16;
    const float* qp = qkv + (size_t)(b * TT + qrow) * 384 + h * 16 + qh * 8;
    float4 x0 = *(const float4*)&qp[0];
    float4 x1 = *(const float4*)&qp[4];
    float xv[8] = {x0.x, x0.y, x0.z, x0.w, x1.x, x1.y, x1.z, x1.w};
#pragma unroll
    for (int j = 0; j < 8; j++) {
      float q = xv[j] * 0.25f;
      _Float16 hi = (_Float16)q;
      _Float16 lo = (_Float16)(q - (float)hi);
      qa[u][j] = (quad < 2) ? hi : lo;
    }
  }

  f32x4_t oacc[2];
  float lacc[2][4];
#pragma unroll
  for (int u = 0; u < 2; u++)
#pragma unroll
    for (int r = 0; r < 4; r++) { oacc[u][r] = 0.f; lacc[u][r] = 0.f; }

  float* Pw = &Pscr[wv][0];

  for (int ks = 0; ks < TT; ks += AKS) {
    __syncthreads();
    // stage K (row layout [key][dim], hi/lo) and V (transposed [dim][key])
    {
      const int key = tid >> 1, hf = tid & 1;
      const float* kp = qkv + (size_t)(b * TT + ks + key) * 384 + 128 + h * 16 + hf * 8;
      float4 k0 = *(const float4*)&kp[0];
      float4 k1 = *(const float4*)&kp[4];
      f16x8 vh, vl;
      split8(k0, k1, vh, vl);
      *(f16x8*)&Khi[key * 16 + hf * 8] = vh;
      *(f16x8*)&Klo[key * 16 + hf * 8] = vl;
      const float* vp = kp + 128;
      float4 v0 = *(const float4*)&vp[0];
      float4 v1 = *(const float4*)&vp[4];
      float vvv[8] = {v0.x, v0.y, v0.z, v0.w, v1.x, v1.y, v1.z, v1.w};
#pragma unroll
      for (int j = 0; j < 8; j++) {
        const int d = hf * 8 + j;
        _Float16 hi = (_Float16)vvv[j];
        Vthi[d * VSTR + key] = hi;
        Vtlo[d * VSTR + key] = (_Float16)(vvv[j] - (float)hi);
      }
    }
    __syncthreads();

    for (int kt = 0; kt < AKS; kt += 16) {
      // QK B-frags: B[k][n=l16]: key = kt+l16, dims (quad&1)*8+j (duplicated)
      f16x8 kfh = *(const f16x8*)&Khi[(kt + l16) * 16 + qh * 8];
      f16x8 kfl = *(const f16x8*)&Klo[(kt + l16) * 16 + qh * 8];
      // PV B-frags: B[k][n=d=l16]: key = kt + (quad&1)*8+j (duplicated)
      const int vo = l16 * VSTR + kt + qh * 8;
      f16x4 va0 = *(const f16x4*)&Vthi[vo];
      f16x4 va1 = *(const f16x4*)&Vthi[vo + 4];
      f16x4 vb0 = *(const f16x4*)&Vtlo[vo];
      f16x4 vb1 = *(const f16x4*)&Vtlo[vo + 4];
      f16x8 vfh, vfl;
#pragma unroll
      for (int i = 0; i < 4; i++) {
        vfh[i] = va0[i]; vfh[4 + i] = va1[i];
        vfl[i] = vb0[i]; vfl[4 + i] = vb1[i];
      }

#pragma unroll
      for (int u = 0; u < 2; u++) {
        f32x4_t s;
#pragma unroll
        for (int r = 0; r < 4; r++) s[r] = 0.f;
        s = __builtin_amdgcn_mfma_f32_16x16x32_f16(qa[u], kfh, s, 0, 0, 0);
        s = __builtin_amdgcn_mfma_f32_16x16x32_f16(qa[u], kfl, s, 0, 0, 0);
        // p = exp(s); C-layout: row(query)=quad*4+r, col(key)=l16
        float p[4];
#pragma unroll
        for (int r = 0; r < 4; r++) {
          p[r] = __expf(s[r]);
          lacc[u][r] += p[r];
        }
        float* ps = Pw + (quad * 4) * 18 + l16;
        ps[0] = p[0]; ps[18] = p[1]; ps[36] = p[2]; ps[54] = p[3];
        __asm__ volatile("s_waitcnt lgkmcnt(0)" ::: "memory");
        // A-frag read: A[m=query=l16][k]: keys (quad&1)*8+j, hi|lo by quad
        const float* pr = Pw + l16 * 18 + qh * 8;
        f16x8 pa;
#pragma unroll
        for (int j = 0; j < 8; j++) {
          float pv = pr[j];
          _Float16 hi = (_Float16)pv;
          _Float16 lo = (_Float16)(pv - (float)hi);
          pa[j] = (quad < 2) ? hi : lo;
        }
        oacc[u] = __builtin_amdgcn_mfma_f32_16x16x32_f16(pa, vfh, oacc[u], 0, 0, 0);
        oacc[u] = __builtin_amdgcn_mfma_f32_16x16x32_f16(pa, vfl, oacc[u], 0, 0, 0);
        __asm__ volatile("s_waitcnt lgkmcnt(0)" ::: "memory");
      }
    }
  }

  // reduce l across the 16 key-columns (lanes of each l16 group), write o
#pragma unroll
  for (int u = 0; u < 2; u++) {
#pragma unroll
    for (int r = 0; r < 4; r++) {
      float lv = lacc[u][r];
      lv += __shfl_xor(lv, 1);
      lv += __shfl_xor(lv, 2);
      lv += __shfl_xor(lv, 4);
      lv += __shfl_xor(lv, 8);
      const float inv = 1.f / lv;
      const int qrow = qb0 + wv * 32 + u * 16 + quad * 4 + r;
      o[(size_t)(b * TT + qrow) * 128 + h * 16 + l16] = oacc[u][r] * inv;
    }
  }
}

// ---------------------------------------------------------------------------
// out = LN(a + bvec) * w + bb
// ---------------------------------------------------------------------------
__global__ __launch_bounds__(256) void add_ln_k(
    const float* __restrict__ a, const float* __restrict__ bvec,
    const float* __restrict__ w, const float* __restrict__ bb,
    float* __restrict__ out)
{
  const int tid = threadIdx.x;
  const int wave = tid >> 6, lane = tid & 63;
  const size_t row = (size_t)blockIdx.x * 4 + wave;
  const float* pa = a + row * 128;
  const float* pb = bvec + row * 128;
  float v0 = pa[lane] + pb[lane];
  float v1 = pa[lane + 64] + pb[lane + 64];
  float s1 = v0 + v1, s2 = v0 * v0 + v1 * v1;
#pragma unroll
  for (int off = 32; off; off >>= 1) {
    s1 += __shfl_down(s1, off);
    s2 += __shfl_down(s2, off);
  }
  s1 = __shfl(s1, 0); s2 = __shfl(s2, 0);
  const float mean = s1 * (1.f / 128.f);
  const float var = s2 * (1.f / 128.f) - mean * mean;
  const float rs = rsqrtf(var + EPSV);
  out[row * 128 + lane]      = (v0 - mean) * rs * w[lane] + bb[lane];
  out[row * 128 + lane + 64] = (v1 - mean) * rs * w[lane + 64] + bb[lane + 64];
}

// ---------------------------------------------------------------------------
// Depthwise causal conv (DC=4) + SiLU
// ---------------------------------------------------------------------------
__global__ __launch_bounds__(256) void conv_silu_k(
    const float* __restrict__ xz, const float* __restrict__ cw,
    const float* __restrict__ cb, float* __restrict__ out)
{
  const int idx = blockIdx.x * 256 + threadIdx.x;
  const int di = idx & 1023;
  const int m = idx >> 10;
  const int t = m & (TT - 1);
  float acc = cb[di];
#pragma unroll
  for (int k = 0; k < 4; k++) {
    int tt = t + k - 3;
    if (tt >= 0) acc += xz[(size_t)(m + k - 3) * 2048 + di] * cw[di * 4 + k];
  }
  out[(size_t)m * 1024 + di] = acc / (1.f + __expf(-acc));
}

// ---------------------------------------------------------------------------
// Chunked selective scan, phase A: local scan, emit P=prod(dA), S=local h.
// ---------------------------------------------------------------------------
__global__ __launch_bounds__(64) void scan_partial_k(
    const float* __restrict__ dt,
    const float* __restrict__ dbc,
    const float* __restrict__ xi,
    const float* __restrict__ Alog,
    float* __restrict__ Pb, float* __restrict__ Sb)
{
  const int slice = blockIdx.x & 15;
  const int c = blockIdx.x >> 4;
  const int b = blockIdx.y;
  const int di = slice * 64 + threadIdx.x;

  float A[NSTATE];
#pragma unroll
  for (int n = 0; n < NSTATE; n++) A[n] = -__expf(Alog[di * NSTATE + n]);
  float h[NSTATE], P[NSTATE];
#pragma unroll
  for (int n = 0; n < NSTATE; n++) { h[n] = 0.f; P[n] = 1.f; }

  const size_t m0 = (size_t)b * TT + (size_t)c * CHUNK;
  for (int t = 0; t < CHUNK; t++) {
    const size_t m = m0 + t;
    const float dtv = dt[m * 1024 + di];
    const float xv  = xi[m * 1024 + di];
    const float dtx = dtv * xv;
#pragma unroll
    for (int n = 0; n < NSTATE; n++) {
      const float Bv = dbc[m * 64 + 32 + n];
      const float dA = __expf(dtv * A[n]);
      h[n] = h[n] * dA + dtx * Bv;
      P[n] *= dA;
    }
  }
  const size_t base = (((size_t)b * NCH + c) * NSTATE) * 1024 + di;
#pragma unroll
  for (int n = 0; n < NSTATE; n++) {
    Pb[base + (size_t)n * 1024] = P[n];
    Sb[base + (size_t)n * 1024] = h[n];
  }
}

// ---------------------------------------------------------------------------
// Phase B: sequential chunk fix-up per (b, di).
// ---------------------------------------------------------------------------
__global__ __launch_bounds__(256) void scan_fix_k(
    float* __restrict__ Pb, const float* __restrict__ Sb)
{
  const int idx = blockIdx.x * 256 + threadIdx.x;
  const int b = idx >> 10;
  const int di = idx & 1023;
  float h[NSTATE];
#pragma unroll
  for (int n = 0; n < NSTATE; n++) h[n] = 0.f;
  for (int c = 0; c < NCH; c++) {
    const size_t base = (((size_t)b * NCH + c) * NSTATE) * 1024 + di;
    float P[NSTATE], S[NSTATE];
#pragma unroll
    for (int n = 0; n < NSTATE; n++) {
      P[n] = Pb[base + (size_t)n * 1024];
      S[n] = Sb[base + (size_t)n * 1024];
    }
#pragma unroll
    for (int n = 0; n < NSTATE; n++) {
      Pb[base + (size_t)n * 1024] = h[n];
      h[n] = P[n] * h[n] + S[n];
    }
  }
}

// ---------------------------------------------------------------------------
// Phase C: re-run each chunk from h_in; y = dot(h,C) + D*x; *= silu(z).
// ---------------------------------------------------------------------------
__global__ __launch_bounds__(64) void scan_final_k(
    const float* __restrict__ dt,
    const float* __restrict__ dbc,
    const float* __restrict__ xi,
    const float* __restrict__ xz,
    const float* __restrict__ Alog,
    const float* __restrict__ Dp,
    const float* __restrict__ Hin,
    float* __restrict__ Y)
{
  const int slice = blockIdx.x & 15;
  const int c = blockIdx.x >> 4;
  const int b = blockIdx.y;
  const int di = slice * 64 + threadIdx.x;

  float A[NSTATE];
#pragma unroll
  for (int n = 0; n < NSTATE; n++) A[n] = -__expf(Alog[di * NSTATE + n]);
  const float Dv = Dp[di];
  float h[NSTATE];
  const size_t hbase = (((size_t)b * NCH + c) * NSTATE) * 1024 + di;
#pragma unroll
  for (int n = 0; n < NSTATE; n++) h[n] = Hin[hbase + (size_t)n * 1024];

  const size_t m0 = (size_t)b * TT + (size_t)c * CHUNK;
  for (int t = 0; t < CHUNK; t++) {
    const size_t m = m0 + t;
    const float dtv = dt[m * 1024 + di];
    const float xv  = xi[m * 1024 + di];
    const float zv  = xz[m * 2048 + 1024 + di];
    const float dtx = dtv * xv;
    float y = 0.f;
#pragma unroll
    for (int n = 0; n < NSTATE; n++) {
      const float Bv = dbc[m * 64 + 32 + n];
      const float Cv = dbc[m * 64 + 48 + n];
      const float dA = __expf(dtv * A[n]);
      h[n] = h[n] * dA + dtx * Bv;
      y += h[n] * Cv;
    }
    y += Dv * xv;
    y *= zv / (1.f + __expf(-zv));
    Y[m * 1024 + di] = y;
  }
}

// ---------------------------------------------------------------------------
extern "C" void kernel_launch(void* const* d_in, const int* in_sizes, int n_in,
                              void* d_out, int out_size, void* d_ws, size_t ws_size,
                              hipStream_t stream)
{
  const float* emb      = (const float*)d_in[0];
  const float* t_wqkv   = (const float*)d_in[1];
  const float* t_bqkv   = (const float*)d_in[2];
  const float* t_wo     = (const float*)d_in[3];
  const float* t_bo     = (const float*)d_in[4];
  const float* t_ln1w   = (const float*)d_in[5];
  const float* t_ln1b   = (const float*)d_in[6];
  const float* t_w1     = (const float*)d_in[7];
  const float* t_b1     = (const float*)d_in[8];
  const float* t_w2     = (const float*)d_in[9];
  const float* t_b2     = (const float*)d_in[10];
  const float* t_ln2w   = (const float*)d_in[11];
  const float* t_ln2b   = (const float*)d_in[12];
  const float* w_in     = (const float*)d_in[13];
  const float* b_in     = (const float*)d_in[14];
  const float* m_inproj = (const float*)d_in[15];
  const float* m_convw  = (const float*)d_in[16];
  const float* m_convb  = (const float*)d_in[17];
  const float* m_xproj  = (const float*)d_in[18];
  const float* m_dtw    = (const float*)d_in[19];
  const float* m_dtb    = (const float*)d_in[20];
  const float* m_Alog   = (const float*)d_in[21];
  const float* m_D      = (const float*)d_in[22];
  const float* m_outproj= (const float*)d_in[23];
  const float* w_out    = (const float*)d_in[24];
  const float* b_out    = (const float*)d_in[25];

  float* ws = (float*)d_ws;
  float* X0   = ws;                               // M*512
  float* X1   = X0 + (size_t)MM * 512;            // M*512
  float* Abuf = X1 + (size_t)MM * 512;            // M*2048 (qkv | ff1 | xz)
  float* Bf   = Abuf + (size_t)MM * 2048;         // M*1024 (xi_act)
  float* Cf   = Bf + (size_t)MM * 1024;           // M*1024 (wo-out | ff2 | dt)
  float* Yb   = Cf + (size_t)MM * 1024;           // M*1024 (attn o | scan y)
  float* Db   = Yb + (size_t)MM * 1024;           // M*64   (dbc)

  dim3 blk(256);
  auto gemm = [&](const float* A, int lda, const float* W, const float* bias,
                  float* C, int N, int K, int act, int S, float* P, bool tn64) {
    dim3 g(N / (tn64 ? 64 : 128), MM / 128, S);
    if (tn64)
      hipLaunchKernelGGL(gemm_mfma_t<64>, g, blk, 0, stream,
                         A, lda, W, S == 1 ? bias : nullptr, C, P, N, K, S, act);
    else
      hipLaunchKernelGGL(gemm_mfma_t<128>, g, blk, 0, stream,
                         A, lda, W, S == 1 ? bias : nullptr, C, P, N, K, S, act);
    if (S > 1) {
      int stride4 = (MM * N) / 4;
      hipLaunchKernelGGL(reduce_k, dim3(stride4 / 256), blk, 0, stream,
                         P, bias, C, N - 1, S, act, stride4);
    }
  };

  const float* x = emb;
  for (int l = 0; l < NTT; l++) {
    // qkv: N=384 K=128
    gemm(x, 128, t_wqkv + (size_t)l * 384 * 128, t_bqkv + l * 384,
         Abuf, 384, 128, 0, 1, nullptr, false);
    // fused MFMA flash attention -> Yb
    hipLaunchKernelGGL(attn_mfma_k, dim3(TT / 128, HB * 8), blk, 0, stream,
                       Abuf, Yb);
    // wo: N=128 K=128 -> TN64, S=2, partials in X1
    gemm(Yb, 128, t_wo + (size_t)l * 128 * 128, t_bo + l * 128,
         Cf, 128, 128, 0, 2, X1, true);
    hipLaunchKernelGGL(add_ln_k, dim3(MM / 4), blk, 0, stream,
                       x, Cf, t_ln1w + l * 128, t_ln1b + l * 128, X0);
    // w1: N=2048 K=128
    gemm(X0, 128, t_w1 + (size_t)l * 2048 * 128, t_b1 + l * 2048,
         Abuf, 2048, 128, 1, 1, nullptr, false);
    // w2: N=128 K=2048 -> S=8, partials in Yb
    gemm(Abuf, 2048, t_w2 + (size_t)l * 128 * 2048, t_b2 + l * 128,
         Cf, 128, 2048, 0, 8, Yb, false);
    hipLaunchKernelGGL(add_ln_k, dim3(MM / 4), blk, 0, stream,
                       X0, Cf, t_ln2w + l * 128, t_ln2b + l * 128, X0);
    x = X0;
  }

  // w_in: N=512 K=128
  gemm(X0, 128, w_in, b_in, X1, 512, 128, 0, 1, nullptr, false);

  float* xc = X1;
  float* xo = X0;
  for (int l = 0; l < NMM; l++) {
    // inproj: N=2048 K=512
    gemm(xc, 512, m_inproj + (size_t)l * 2048 * 512, nullptr,
         Abuf, 2048, 512, 0, 1, nullptr, false);
    hipLaunchKernelGGL(conv_silu_k, dim3(MM * 1024 / 256), blk, 0, stream,
                       Abuf, m_convw + (size_t)l * 1024 * 4, m_convb + l * 1024, Bf);
    // xproj: N=64 K=1024 -> TN64, S=4, partials in xo
    gemm(Bf, 1024, m_xproj + (size_t)l * 64 * 1024, nullptr,
         Db, 64, 1024, 0, 4, xo, true);
    // dtw: N=1024 K=32, softplus
    gemm(Db, 64, m_dtw + (size_t)l * 1024 * 32, m_dtb + l * 1024,
         Cf, 1024, 32, 2, 1, nullptr, false);

    float* Pb = xo;
    float* Sb = xo + (size_t)HB * NCH * NSTATE * 1024;
    hipLaunchKernelGGL(scan_partial_k, dim3(16 * NCH, HB), dim3(64), 0, stream,
                       Cf, Db, Bf, m_Alog + (size_t)l * 1024 * 16, Pb, Sb);
    hipLaunchKernelGGL(scan_fix_k, dim3(MM / 1024 * 4), blk, 0, stream, Pb, Sb);
    hipLaunchKernelGGL(scan_final_k, dim3(16 * NCH, HB), dim3(64), 0, stream,
                       Cf, Db, Bf, Abuf,
                       m_Alog + (size_t)l * 1024 * 16, m_D + l * 1024, Pb, Yb);

    // outproj: N=512 K=1024 -> S=2, partials in Abuf
    gemm(Yb, 1024, m_outproj + (size_t)l * 512 * 1024, nullptr,
         xo, 512, 1024, 0, 2, Abuf, false);
    float* tmp = xc; xc = xo; xo = tmp;
  }

  // w_out: N=128 K=512 -> S=4, partials in Yb
  gemm(xc, 512, w_out, b_out, (float*)d_out, 128, 512, 0, 4, Yb, false);
}